// Round 10
// baseline (1827.960 us; speedup 1.0000x reference)
//
#include <hip/hip_runtime.h>
#include <hip/hip_bf16.h>
#include <hip/hip_fp16.h>
#include <math.h>

typedef __hip_bfloat16 bf16;
#define NEG_SLOPE 0.2f
#define SFLAG (1 << 30)

#define NSEG 25
struct Seg { const void* src; int n; int off; };
struct Tab { Seg s[NSEG]; };

struct MA {
    Tab tab; float* wf; int* flag;
    const int* srcArr; const int* dstArr;
    int E, N, EA, NBs, EB, GBq, B;
    int* deg; int* rank; int* st; int* offs; int* csr; int* bcnt; int* bgen;
    const void* xraw;
    const float *aeW,*aeb,*a1Wl,*a1bl,*a1Wr,*a1br,*a1att,*a1b;
    const float *a2Wl,*a2bl,*a2Wr,*a2br,*a2att,*a2b;
    const float *clW,*clb,*gWl,*gbl,*gWr,*gbr,*gatt,*gb,*fcW,*fcb,*clf;
    __half* hxl; float* fB; float* fC;
    const int* focal; void* out;
};

// ====== setup: dtype detect + zero deg/st/barrier state ======================
__global__ void k_setup(const unsigned short* __restrict__ x, int* __restrict__ flag,
                        int* __restrict__ zbase, int n) {
    for (int i = blockIdx.x * blockDim.x + threadIdx.x; i < n; i += gridDim.x * blockDim.x)
        zbase[i] = 0;
    if (blockIdx.x == 0) {
        __shared__ int cnt;
        if (threadIdx.x == 0) cnt = 0;
        __syncthreads();
        int local = 0;
        for (int i = threadIdx.x; i < 2048; i += blockDim.x) {
            unsigned short w = x[2 * i];
            int e = (w >> 7) & 0xFF;
            if (e >= 0x90) local++;
        }
        atomicAdd(&cnt, local);
        __syncthreads();
        if (threadIdx.x == 0) flag[0] = (cnt > 100) ? 1 : 0;  // 1 => inputs are f32
    }
}

// ====== grid barrier (all blocks resident) ===================================
__device__ __forceinline__ void gbar(int* cnt, int* gen, int target) {
    __threadfence();
    __syncthreads();
    if (threadIdx.x == 0) {
        int nb = gridDim.x;
        int a = __hip_atomic_fetch_add(cnt, 1, __ATOMIC_ACQ_REL, __HIP_MEMORY_SCOPE_AGENT);
        if (a == nb - 1) {
            __hip_atomic_store(cnt, 0, __ATOMIC_RELAXED, __HIP_MEMORY_SCOPE_AGENT);
            __hip_atomic_fetch_add(gen, 1, __ATOMIC_ACQ_REL, __HIP_MEMORY_SCOPE_AGENT);
        } else {
            while (__hip_atomic_load(gen, __ATOMIC_ACQUIRE, __HIP_MEMORY_SCOPE_AGENT) < target) {}
        }
    }
    __syncthreads();
}

// ====== GAT H=4 phase (R8 layout: wave/dst, reg-csr, 16 lanes x 8ch) =========
__device__ __forceinline__ void gat4_phase(const MA& A, const __half* xl, const float* xr,
                                           const float* att, const float* bias, float* out) {
    int wave = threadIdx.x >> 6, lane = threadIdx.x & 63;
    int grp = lane >> 4, sub = lane & 15;
    for (int q = blockIdx.x; q < A.GBq; q += gridDim.x) {
        int d = q * 4 + wave;
        if (d >= A.N) continue;
        int i0 = A.offs[d], i1 = A.offs[d + 1];

        float xrd[8], av[8], acc[8];
        {
            const float4* p4 = (const float4*)(xr + (size_t)d * 128 + sub * 8);
            float4 a = p4[0], b = p4[1];
            xrd[0]=a.x; xrd[1]=a.y; xrd[2]=a.z; xrd[3]=a.w;
            xrd[4]=b.x; xrd[5]=b.y; xrd[6]=b.z; xrd[7]=b.w;
            const float4* t4 = (const float4*)(att + sub * 8);
            float4 c = t4[0], e = t4[1];
            av[0]=c.x; av[1]=c.y; av[2]=c.z; av[3]=c.w;
            av[4]=e.x; av[5]=e.y; av[6]=e.z; av[7]=e.w;
        }
        #pragma unroll
        for (int c = 0; c < 8; c++) acc[c] = 0.f;
        float sm = 0.f;

        auto proc = [&](float4 raw) {
            const __half2* h = (const __half2*)&raw;
            float v[8];
            float2 f;
            f = __half22float2(h[0]); v[0] = f.x; v[1] = f.y;
            f = __half22float2(h[1]); v[2] = f.x; v[3] = f.y;
            f = __half22float2(h[2]); v[4] = f.x; v[5] = f.y;
            f = __half22float2(h[3]); v[6] = f.x; v[7] = f.y;
            float p = 0.f;
            #pragma unroll
            for (int c = 0; c < 8; c++) {
                float u = v[c] + xrd[c];
                u = (u > 0.f) ? u : NEG_SLOPE * u;
                p += u * av[c];
            }
            p += __shfl_xor(p, 1);
            p += __shfl_xor(p, 2);
            p += __shfl_xor(p, 4);
            p += __shfl_xor(p, 8);
            float w = __expf(fminf(p, 80.f));
            sm += w;
            #pragma unroll
            for (int c = 0; c < 8; c++) acc[c] += w * v[c];
        };

        for (int base = i0; base < i1; base += 64) {
            int cnt = min(i1 - base, 64);
            int myv = (lane < cnt) ? A.csr[base + lane] : 0;
            int m16 = cnt >> 4;
            for (int qq = 0; qq < m16; qq++) {
                int bb = qq * 16 + grp;
                int s0 = __shfl(myv, bb);
                int s1 = __shfl(myv, bb + 4);
                int s2 = __shfl(myv, bb + 8);
                int s3 = __shfl(myv, bb + 12);
                float4 r0 = *(const float4*)(xl + (size_t)s0 * 128 + sub * 8);
                float4 r1 = *(const float4*)(xl + (size_t)s1 * 128 + sub * 8);
                float4 r2 = *(const float4*)(xl + (size_t)s2 * 128 + sub * 8);
                float4 r3 = *(const float4*)(xl + (size_t)s3 * 128 + sub * 8);
                proc(r0); proc(r1); proc(r2); proc(r3);
            }
            for (int j = m16 * 16 + grp; j < cnt; j += 4) {
                int s = __shfl(myv, j);
                float4 r = *(const float4*)(xl + (size_t)s * 128 + sub * 8);
                proc(r);
            }
        }

        sm += __shfl_xor(sm, 16); sm += __shfl_xor(sm, 32);
        #pragma unroll
        for (int c = 0; c < 8; c++) {
            acc[c] += __shfl_xor(acc[c], 16);
            acc[c] += __shfl_xor(acc[c], 32);
        }
        if (grp == 0) {
            float inv = 1.f / (sm + 1e-16f);
            const float4* b4p = (const float4*)(bias + sub * 8);
            float4 b0 = b4p[0], b1 = b4p[1];
            float4 o0, o1;
            o0.x = fmaxf(acc[0] * inv + b0.x, 0.f);
            o0.y = fmaxf(acc[1] * inv + b0.y, 0.f);
            o0.z = fmaxf(acc[2] * inv + b0.z, 0.f);
            o0.w = fmaxf(acc[3] * inv + b0.w, 0.f);
            o1.x = fmaxf(acc[4] * inv + b1.x, 0.f);
            o1.y = fmaxf(acc[5] * inv + b1.y, 0.f);
            o1.z = fmaxf(acc[6] * inv + b1.z, 0.f);
            o1.w = fmaxf(acc[7] * inv + b1.w, 0.f);
            float4* op = (float4*)(out + (size_t)d * 128 + sub * 8);
            op[0] = o0; op[1] = o1;
        }
    }
}

// ====== GAT H=1 phase ========================================================
__device__ __forceinline__ void gatg_phase(const MA& A, const __half* xl, const float* xr,
                                           const float* att, const float* bias, float* out) {
    int wave = threadIdx.x >> 6, lane = threadIdx.x & 63;
    int grp = lane >> 3, sub = lane & 7;
    for (int q = blockIdx.x; q < A.GBq; q += gridDim.x) {
        int d = q * 4 + wave;
        if (d >= A.N) continue;
        int i0 = A.offs[d], i1 = A.offs[d + 1];

        float xrd[4], av[4], acc[4];
        {
            float4 a = *(const float4*)(xr + (size_t)d * 32 + sub * 4);
            xrd[0]=a.x; xrd[1]=a.y; xrd[2]=a.z; xrd[3]=a.w;
            float4 c = *(const float4*)(att + sub * 4);
            av[0]=c.x; av[1]=c.y; av[2]=c.z; av[3]=c.w;
        }
        #pragma unroll
        for (int c = 0; c < 4; c++) acc[c] = 0.f;
        float sm = 0.f;

        auto proc = [&](float2 raw) {
            const __half2* h = (const __half2*)&raw;
            float v[4];
            float2 f;
            f = __half22float2(h[0]); v[0] = f.x; v[1] = f.y;
            f = __half22float2(h[1]); v[2] = f.x; v[3] = f.y;
            float p = 0.f;
            #pragma unroll
            for (int c = 0; c < 4; c++) {
                float u = v[c] + xrd[c];
                u = (u > 0.f) ? u : NEG_SLOPE * u;
                p += u * av[c];
            }
            p += __shfl_xor(p, 1);
            p += __shfl_xor(p, 2);
            p += __shfl_xor(p, 4);
            float w = __expf(fminf(p, 80.f));
            sm += w;
            #pragma unroll
            for (int c = 0; c < 4; c++) acc[c] += w * v[c];
        };

        for (int base = i0; base < i1; base += 64) {
            int cnt = min(i1 - base, 64);
            int myv = (lane < cnt) ? A.csr[base + lane] : 0;
            int m16 = cnt >> 4;
            for (int qq = 0; qq < m16; qq++) {
                int b8 = qq * 16 + grp;
                int s0 = __shfl(myv, b8);
                int s1 = __shfl(myv, b8 + 8);
                float2 r0 = *(const float2*)(xl + (size_t)s0 * 32 + sub * 4);
                float2 r1 = *(const float2*)(xl + (size_t)s1 * 32 + sub * 4);
                proc(r0); proc(r1);
            }
            for (int j = m16 * 16 + grp; j < cnt; j += 8) {
                int s = __shfl(myv, j);
                float2 r = *(const float2*)(xl + (size_t)s * 32 + sub * 4);
                proc(r);
            }
        }

        sm += __shfl_xor(sm, 8); sm += __shfl_xor(sm, 16); sm += __shfl_xor(sm, 32);
        #pragma unroll
        for (int c = 0; c < 4; c++) {
            acc[c] += __shfl_xor(acc[c], 8);
            acc[c] += __shfl_xor(acc[c], 16);
            acc[c] += __shfl_xor(acc[c], 32);
        }
        if (grp == 0) {
            float inv = 1.f / (sm + 1e-16f);
            float4 b = *(const float4*)(bias + sub * 4);
            float4 o;
            o.x = fmaxf(acc[0] * inv + b.x, 0.f);
            o.y = fmaxf(acc[1] * inv + b.y, 0.f);
            o.z = fmaxf(acc[2] * inv + b.z, 0.f);
            o.w = fmaxf(acc[3] * inv + b.w, 0.f);
            *(float4*)(out + (size_t)d * 32 + sub * 4) = o;
        }
    }
}

// ====== dual linear FIN=128 -> 128 phase =====================================
__device__ __forceinline__ void lin2_phase(const MA& A, float* smem, const float* x,
                                           const float* Wl, const float* bl,
                                           const float* Wr, const float* br,
                                           __half* outl, float* outr) {
    constexpr int NTP = 36;
    int t = threadIdx.x;
    for (int tile = blockIdx.x; tile < A.EB; tile += gridDim.x) {
        int nb2 = tile * 32;
        const float4* x4 = (const float4*)x;
        for (int idx = t; idx < 32 * 32; idx += 256) {
            int node = idx >> 5, k4 = idx & 31;
            float4 v = x4[(size_t)(nb2 + node) * 32 + k4];
            smem[(k4 * 4 + 0) * NTP + node] = v.x;
            smem[(k4 * 4 + 1) * NTP + node] = v.y;
            smem[(k4 * 4 + 2) * NTP + node] = v.z;
            smem[(k4 * 4 + 3) * NTP + node] = v.w;
        }
        __syncthreads();

        int j = t & 63, g0 = t >> 6;
        float aL0[2][4], aL1[2][4], aR0[2][4], aR1[2][4];
        #pragma unroll
        for (int g = 0; g < 2; g++)
            #pragma unroll
            for (int c = 0; c < 4; c++) { aL0[g][c]=0.f; aL1[g][c]=0.f; aR0[g][c]=0.f; aR1[g][c]=0.f; }

        #pragma unroll 4
        for (int k = 0; k < 128; k++) {
            float wl0 = Wl[(size_t)k * 128 + j];
            float wl1 = Wl[(size_t)k * 128 + j + 64];
            float wr0 = Wr[(size_t)k * 128 + j];
            float wr1 = Wr[(size_t)k * 128 + j + 64];
            #pragma unroll
            for (int g = 0; g < 2; g++) {
                const float4 xv = *(const float4*)&smem[k * NTP + (g0 + g * 4) * 4];
                aL0[g][0] += wl0 * xv.x; aL0[g][1] += wl0 * xv.y; aL0[g][2] += wl0 * xv.z; aL0[g][3] += wl0 * xv.w;
                aL1[g][0] += wl1 * xv.x; aL1[g][1] += wl1 * xv.y; aL1[g][2] += wl1 * xv.z; aL1[g][3] += wl1 * xv.w;
                aR0[g][0] += wr0 * xv.x; aR0[g][1] += wr0 * xv.y; aR0[g][2] += wr0 * xv.z; aR0[g][3] += wr0 * xv.w;
                aR1[g][0] += wr1 * xv.x; aR1[g][1] += wr1 * xv.y; aR1[g][2] += wr1 * xv.z; aR1[g][3] += wr1 * xv.w;
            }
        }

        float bl0 = bl[j], bl1 = bl[j + 64], br0 = br[j], br1 = br[j + 64];
        #pragma unroll
        for (int g = 0; g < 2; g++) {
            int n0 = nb2 + (g0 + g * 4) * 4;
            #pragma unroll
            for (int c = 0; c < 4; c++) {
                size_t row = (size_t)(n0 + c) * 128;
                outl[row + j]      = __float2half(aL0[g][c] + bl0);
                outl[row + j + 64] = __float2half(aL1[g][c] + bl1);
                outr[row + j]      = aR0[g][c] + br0;
                outr[row + j + 64] = aR1[g][c] + br1;
            }
        }
        __syncthreads();
    }
}

// ====== dual linear FIN=128 -> 32 (global) phase =============================
__device__ __forceinline__ void ling_phase(const MA& A, float* smem, const float* x,
                                           const float* Wl, const float* bl,
                                           const float* Wr, const float* br,
                                           __half* outl, float* outr) {
    constexpr int NTP = 36;
    int t = threadIdx.x;
    for (int tile = blockIdx.x; tile < A.EB; tile += gridDim.x) {
        int nb2 = tile * 32;
        const float4* x4 = (const float4*)x;
        for (int idx = t; idx < 32 * 32; idx += 256) {
            int node = idx >> 5, k4 = idx & 31;
            float4 v = x4[(size_t)(nb2 + node) * 32 + k4];
            smem[(k4 * 4 + 0) * NTP + node] = v.x;
            smem[(k4 * 4 + 1) * NTP + node] = v.y;
            smem[(k4 * 4 + 2) * NTP + node] = v.z;
            smem[(k4 * 4 + 3) * NTP + node] = v.w;
        }
        __syncthreads();

        int j = t & 31, g0 = t >> 5;
        float aL[4], aR[4];
        #pragma unroll
        for (int c = 0; c < 4; c++) { aL[c] = 0.f; aR[c] = 0.f; }

        #pragma unroll 4
        for (int k = 0; k < 128; k++) {
            float wl = Wl[(size_t)k * 32 + j];
            float wr = Wr[(size_t)k * 32 + j];
            const float4 xv = *(const float4*)&smem[k * NTP + g0 * 4];
            aL[0] += wl * xv.x; aL[1] += wl * xv.y; aL[2] += wl * xv.z; aL[3] += wl * xv.w;
            aR[0] += wr * xv.x; aR[1] += wr * xv.y; aR[2] += wr * xv.z; aR[3] += wr * xv.w;
        }

        float blj = bl[j], brj = br[j];
        #pragma unroll
        for (int c = 0; c < 4; c++) {
            size_t row = (size_t)(nb2 + g0 * 4 + c) * 32;
            outl[row + j] = __float2half(aL[c] + blj);
            outr[row + j] = aR[c] + brj;
        }
        __syncthreads();
    }
}

// ====== THE MEGAKERNEL =======================================================
__launch_bounds__(256, 3)
__global__ void k_mega(MA A) {
    __shared__ float smem[4752];
    __shared__ int swsum[4], swoff[4];
    __shared__ int s_stot, s_prev;
    int t = threadIdx.x;
    int gid = blockIdx.x * 256 + t;
    int gsz = gridDim.x * 256;
    int f32 = A.flag[0];

    // ---- phase 0: convert weights + degree count with rank capture ----
    for (int s = 0; s < NSEG; s++) {
        Seg sg = A.tab.s[s];
        for (int i = gid; i < sg.n; i += gsz) {
            float v = f32 ? ((const float*)sg.src)[i]
                          : __bfloat162float(((const bf16*)sg.src)[i]);
            A.wf[sg.off + i] = v;
        }
    }
    for (int e = gid; e < A.EA; e += gsz) {
        int d = (e < A.E) ? A.dstArr[e] : (e - A.E);
        A.rank[e] = atomicAdd(&A.deg[d], 1);
    }
    gbar(A.bcnt, A.bgen, 1);

    // ---- phase 1: exclusive scan with lookback (blocks < NBs) ----
    if (blockIdx.x < A.NBs) {
        int tile = blockIdx.x;
        int lane = t & 63, wid = t >> 6;
        int i0 = tile * 1024 + t * 4;
        int d0 = 0, d1 = 0, d2 = 0, d3 = 0;
        if (i0 + 3 < A.N) {
            int4 v = *(const int4*)(A.deg + i0);
            d0 = v.x; d1 = v.y; d2 = v.z; d3 = v.w;
        } else {
            if (i0 < A.N) d0 = A.deg[i0];
            if (i0 + 1 < A.N) d1 = A.deg[i0 + 1];
            if (i0 + 2 < A.N) d2 = A.deg[i0 + 2];
        }
        int tsum = d0 + d1 + d2 + d3;
        int x = tsum;
        #pragma unroll
        for (int o = 1; o < 64; o <<= 1) {
            int y = __shfl_up(x, o);
            if (lane >= o) x += y;
        }
        if (lane == 63) swsum[wid] = x;
        __syncthreads();
        if (t == 0) {
            int r = 0;
            #pragma unroll
            for (int w = 0; w < 4; w++) { swoff[w] = r; r += swsum[w]; }
            s_stot = r;
        }
        __syncthreads();
        if (t == 0) {
            int prev = 0;
            if (tile > 0) {
                int vv;
                while ((((vv = __hip_atomic_load(&A.st[tile - 1], __ATOMIC_ACQUIRE,
                                                 __HIP_MEMORY_SCOPE_AGENT))) & SFLAG) == 0) {}
                prev = vv & ~SFLAG;
            }
            __hip_atomic_store(&A.st[tile], (prev + s_stot) | SFLAG, __ATOMIC_RELEASE,
                               __HIP_MEMORY_SCOPE_AGENT);
            s_prev = prev;
            if (tile == A.NBs - 1) A.offs[A.N] = prev + s_stot;
        }
        __syncthreads();
        int base = s_prev + swoff[wid] + (x - tsum);
        if (i0 < A.N)     A.offs[i0]     = base;
        if (i0 + 1 < A.N) A.offs[i0 + 1] = base + d0;
        if (i0 + 2 < A.N) A.offs[i0 + 2] = base + d0 + d1;
        if (i0 + 3 < A.N) A.offs[i0 + 3] = base + d0 + d1 + d2;
    }
    gbar(A.bcnt, A.bgen, 2);

    // ---- phase 2: CSR fill (no atomics, rank trick) + embed + conv1 linear --
    for (int e = gid; e < A.EA; e += gsz) {
        int d, s;
        if (e < A.E) { d = A.dstArr[e]; s = A.srcArr[e]; } else { d = s = e - A.E; }
        A.csr[A.offs[d] + A.rank[e]] = s;
    }
    {
        constexpr int NTP = 36;
        float* xs = smem;
        float* axs = smem + 3600;
        for (int tile = blockIdx.x; tile < A.EB; tile += gridDim.x) {
            int nb2 = tile * 32;
            if (f32) {
                const float4* x4 = (const float4*)A.xraw;
                for (int idx = t; idx < 32 * 25; idx += 256) {
                    int node = idx / 25, k4 = idx % 25;
                    float4 v = x4[(size_t)(nb2 + node) * 25 + k4];
                    xs[(k4 * 4 + 0) * NTP + node] = v.x;
                    xs[(k4 * 4 + 1) * NTP + node] = v.y;
                    xs[(k4 * 4 + 2) * NTP + node] = v.z;
                    xs[(k4 * 4 + 3) * NTP + node] = v.w;
                }
            } else {
                const ushort4* xu = (const ushort4*)A.xraw;
                for (int idx = t; idx < 32 * 25; idx += 256) {
                    int node = idx / 25, k4 = idx % 25;
                    ushort4 u = xu[(size_t)(nb2 + node) * 25 + k4];
                    xs[(k4 * 4 + 0) * NTP + node] = __uint_as_float((unsigned)u.x << 16);
                    xs[(k4 * 4 + 1) * NTP + node] = __uint_as_float((unsigned)u.y << 16);
                    xs[(k4 * 4 + 2) * NTP + node] = __uint_as_float((unsigned)u.z << 16);
                    xs[(k4 * 4 + 3) * NTP + node] = __uint_as_float((unsigned)u.w << 16);
                }
            }
            __syncthreads();
            {
                int j = t & 31, g0 = t >> 5;
                float a0 = 0.f, a1 = 0.f, a2 = 0.f, a3 = 0.f;
                #pragma unroll 10
                for (int k = 0; k < 100; k++) {
                    float w = A.aeW[k * 32 + j];
                    const float4 xv = *(const float4*)&xs[k * NTP + g0 * 4];
                    a0 += w * xv.x; a1 += w * xv.y; a2 += w * xv.z; a3 += w * xv.w;
                }
                float bj = A.aeb[j];
                axs[j * NTP + g0 * 4 + 0] = fmaxf(a0 + bj, 0.f);
                axs[j * NTP + g0 * 4 + 1] = fmaxf(a1 + bj, 0.f);
                axs[j * NTP + g0 * 4 + 2] = fmaxf(a2 + bj, 0.f);
                axs[j * NTP + g0 * 4 + 3] = fmaxf(a3 + bj, 0.f);
            }
            __syncthreads();
            {
                int j = t & 63, g0 = t >> 6;
                float aL0[2][4], aL1[2][4], aR0[2][4], aR1[2][4];
                #pragma unroll
                for (int g = 0; g < 2; g++)
                    #pragma unroll
                    for (int c = 0; c < 4; c++) { aL0[g][c]=0.f; aL1[g][c]=0.f; aR0[g][c]=0.f; aR1[g][c]=0.f; }
                #pragma unroll 4
                for (int k = 0; k < 32; k++) {
                    float wl0 = A.a1Wl[k * 128 + j];
                    float wl1 = A.a1Wl[k * 128 + j + 64];
                    float wr0 = A.a1Wr[k * 128 + j];
                    float wr1 = A.a1Wr[k * 128 + j + 64];
                    #pragma unroll
                    for (int g = 0; g < 2; g++) {
                        const float4 xv = *(const float4*)&axs[k * NTP + (g0 + g * 4) * 4];
                        aL0[g][0] += wl0 * xv.x; aL0[g][1] += wl0 * xv.y; aL0[g][2] += wl0 * xv.z; aL0[g][3] += wl0 * xv.w;
                        aL1[g][0] += wl1 * xv.x; aL1[g][1] += wl1 * xv.y; aL1[g][2] += wl1 * xv.z; aL1[g][3] += wl1 * xv.w;
                        aR0[g][0] += wr0 * xv.x; aR0[g][1] += wr0 * xv.y; aR0[g][2] += wr0 * xv.z; aR0[g][3] += wr0 * xv.w;
                        aR1[g][0] += wr1 * xv.x; aR1[g][1] += wr1 * xv.y; aR1[g][2] += wr1 * xv.z; aR1[g][3] += wr1 * xv.w;
                    }
                }
                float bl0 = A.a1bl[j], bl1 = A.a1bl[j + 64], br0 = A.a1br[j], br1 = A.a1br[j + 64];
                #pragma unroll
                for (int g = 0; g < 2; g++) {
                    int n0 = nb2 + (g0 + g * 4) * 4;
                    #pragma unroll
                    for (int c = 0; c < 4; c++) {
                        size_t row = (size_t)(n0 + c) * 128;
                        A.hxl[row + j]      = __float2half(aL0[g][c] + bl0);
                        A.hxl[row + j + 64] = __float2half(aL1[g][c] + bl1);
                        A.fB[row + j]       = aR0[g][c] + br0;
                        A.fB[row + j + 64]  = aR1[g][c] + br1;
                    }
                }
            }
            __syncthreads();
        }
    }
    gbar(A.bcnt, A.bgen, 3);

    // ---- phase 3: conv1 gather ----
    gat4_phase(A, A.hxl, A.fB, A.a1att, A.a1b, A.fC);
    gbar(A.bcnt, A.bgen, 4);

    // ---- phase 4: conv2 linear ----
    lin2_phase(A, smem, A.fC, A.a2Wl, A.a2bl, A.a2Wr, A.a2br, A.hxl, A.fB);
    gbar(A.bcnt, A.bgen, 5);

    // ---- phase 5: conv2 gather ----
    gat4_phase(A, A.hxl, A.fB, A.a2att, A.a2b, A.fC);
    gbar(A.bcnt, A.bgen, 6);

    // ---- phase 6: global linear ----
    ling_phase(A, smem, A.fC, A.gWl, A.gbl, A.gWr, A.gbr, A.hxl, A.fB);
    gbar(A.bcnt, A.bgen, 7);

    // ---- phase 7: global gather ----
    float* gf = A.fB + (size_t)A.N * 32;
    gatg_phase(A, A.hxl, A.fB, A.gatt, A.gb, gf);
    gbar(A.bcnt, A.bgen, 8);

    // ---- phase 8: tail ----
    if (blockIdx.x < A.B) {
        int b = blockIdx.x;
        float* comb = smem;
        float* ssb = smem + 64;
        if (t < 2) {
            float s = 0.f;
            for (int l = 0; l < 50; l++) s += A.clf[(size_t)b * 100 + l * 2 + t];
            ssb[t] = s / 50.f;
        }
        if (t < 32) comb[t] = gf[(size_t)A.focal[b] * 32 + t];
        __syncthreads();
        if (t < 32) comb[32 + t] = ssb[0] * A.clW[t] + ssb[1] * A.clW[32 + t] + A.clb[t];
        __syncthreads();
        if (t < 60) {
            float acc = A.fcb[t];
            #pragma unroll 16
            for (int k = 0; k < 64; k++) acc += comb[k] * A.fcW[k * 60 + t];
            if (f32) ((float*)A.out)[b * 60 + t] = acc;
            else ((bf16*)A.out)[b * 60 + t] = __float2bfloat16(acc);
        }
    }
}

extern "C" void kernel_launch(void* const* d_in, const int* in_sizes, int n_in,
                              void* d_out, int out_size, void* d_ws, size_t ws_size,
                              hipStream_t stream) {
    const int* edge  = (const int*)d_in[1];
    const int* focal = (const int*)d_in[5];

    const int N = in_sizes[0] / 100;   // 20000
    const int E = in_sizes[1] / 2;     // 320000
    const int B = in_sizes[5];         // 64
    const int EA = E + N;

    const int idxs[NSEG] = {7,8,9,10,11,12,13,14,15,16,17,18,19,20,
                            35,36,37,38,39,40,41,42,43,44, 6};
    float* base = (float*)d_ws;
    int* flag = (int*)base;            // base[0..15] reserved
    float* wf = base + 16;

    MA A;
    int off[NSEG];
    int o = 0;
    for (int i = 0; i < NSEG; i++) {
        A.tab.s[i].src = d_in[idxs[i]];
        A.tab.s[i].n   = in_sizes[idxs[i]];
        A.tab.s[i].off = o;
        off[i] = o;
        o += in_sizes[idxs[i]];
    }
    A.wf = wf; A.flag = flag;
    A.aeW  = wf + off[0];  A.aeb  = wf + off[1];
    A.a1Wl = wf + off[2];  A.a1bl = wf + off[3];
    A.a1Wr = wf + off[4];  A.a1br = wf + off[5];
    A.a1att= wf + off[6];  A.a1b  = wf + off[7];
    A.a2Wl = wf + off[8];  A.a2bl = wf + off[9];
    A.a2Wr = wf + off[10]; A.a2br = wf + off[11];
    A.a2att= wf + off[12]; A.a2b  = wf + off[13];
    A.clW  = wf + off[14]; A.clb  = wf + off[15];
    A.gWl  = wf + off[16]; A.gbl  = wf + off[17];
    A.gWr  = wf + off[18]; A.gbr  = wf + off[19];
    A.gatt = wf + off[20]; A.gb   = wf + off[21];
    A.fcW  = wf + off[22]; A.fcb  = wf + off[23];
    A.clf  = wf + off[24];

    float* p = wf + o + ((4 - (o & 3)) & 3);
    size_t N128 = (size_t)N * 128;
    A.hxl = (__half*)p;      p += (size_t)N * 64;   // xl fp16 [N,128]
    A.fB  = p;               p += N128;             // xr fp32 (global: xrg + gf)
    A.fC  = p;               p += N128;             // h / agent_features fp32
    A.deg  = (int*)p;                // [N]   (16B aligned)
    A.st   = A.deg + N;              // [32]
    A.bcnt = A.st + 32;              // [1]
    A.bgen = A.bcnt + 1;             // [1]
    A.offs = A.bgen + 1;             // [N+1]
    A.rank = A.offs + N + 1;         // [EA]
    A.csr  = A.rank + EA;            // [EA]

    A.srcArr = edge; A.dstArr = edge + E;
    A.E = E; A.N = N; A.EA = EA;
    A.NBs = (N + 1023) / 1024;       // 20 scan tiles
    A.EB = N / 32;                   // 625 linear tiles
    A.GBq = (N + 3) / 4;             // 5000 dst quads
    A.B = B;
    A.xraw = d_in[0];
    A.focal = focal;
    A.out = d_out;

    // setup: detect dtype + zero deg/st/barrier state (N + 34 ints)
    k_setup<<<64, 256, 0, stream>>>((const unsigned short*)d_in[0], flag, A.deg, N + 34);
    // megakernel: 768 blocks x 256 thr, 3 blocks/CU guaranteed co-resident
    k_mega<<<768, 256, 0, stream>>>(A);
}

// Round 11
// 306.708 us; speedup vs baseline: 5.9599x; 5.9599x over previous
//
#include <hip/hip_runtime.h>
#include <hip/hip_bf16.h>
#include <hip/hip_fp16.h>
#include <math.h>

typedef __hip_bfloat16 bf16;
#define NEG_SLOPE 0.2f
#define SFLAG (1 << 30)

// ====== dtype detect (block 0) + zero deg/scan-state =========================
__global__ void k_detect_zero(const unsigned short* __restrict__ x, int* __restrict__ flag,
                              int* __restrict__ zbase, int n) {
    for (int i = blockIdx.x * blockDim.x + threadIdx.x; i < n; i += gridDim.x * blockDim.x)
        zbase[i] = 0;
    if (blockIdx.x == 0) {
        __shared__ int cnt;
        if (threadIdx.x == 0) cnt = 0;
        __syncthreads();
        int local = 0;
        for (int i = threadIdx.x; i < 2048; i += blockDim.x) {
            unsigned short w = x[2 * i];
            int e = (w >> 7) & 0xFF;
            if (e >= 0x90) local++;
        }
        atomicAdd(&cnt, local);
        __syncthreads();
        if (threadIdx.x == 0) flag[0] = (cnt > 100) ? 1 : 0;  // 1 => inputs are f32
    }
}

#define NSEG 25
struct Seg { const void* src; int n; int off; };
struct Tab { Seg s[NSEG]; };

// ====== convert weights to fp32 + degree count with rank capture =============
__global__ void k_convert(Tab tab, float* __restrict__ dst, const int* __restrict__ flag,
                          const int* __restrict__ dstArr, int E, int N,
                          int* __restrict__ deg, int* __restrict__ rank) {
    int f32mode = flag[0];
    int gid = blockIdx.x * blockDim.x + threadIdx.x;
    int gsz = gridDim.x * blockDim.x;
    for (int s = 0; s < NSEG; s++) {
        Seg sg = tab.s[s];
        for (int i = gid; i < sg.n; i += gsz) {
            float v = f32mode ? ((const float*)sg.src)[i]
                              : __bfloat162float(((const bf16*)sg.src)[i]);
            dst[sg.off + i] = v;
        }
    }
    int EA = E + N;
    for (int e = gid; e < EA; e += gsz) {
        int d = (e < E) ? dstArr[e] : (e - E);
        rank[e] = atomicAdd(&deg[d], 1);
    }
}

// ====== single-kernel chained-lookback exclusive scan ========================
__launch_bounds__(1024)
__global__ void k_scanf(const int* __restrict__ deg, int* __restrict__ offs,
                        int n, int* __restrict__ st, int nb) {
    __shared__ int ws[16];
    __shared__ int stot, sprev;
    int tile = blockIdx.x;
    int i = tile * 1024 + threadIdx.x;
    int lane = threadIdx.x & 63, wid = threadIdx.x >> 6;
    int v = (i < n) ? deg[i] : 0;
    int x = v;
    #pragma unroll
    for (int o = 1; o < 64; o <<= 1) {
        int y = __shfl_up(x, o);
        if (lane >= o) x += y;
    }
    if (lane == 63) ws[wid] = x;
    __syncthreads();
    if (wid == 0) {
        int w = (lane < 16) ? ws[lane] : 0;
        int s = w;
        #pragma unroll
        for (int o = 1; o < 16; o <<= 1) {
            int y = __shfl_up(s, o);
            if (lane >= o) s += y;
        }
        if (lane < 16) ws[lane] = s - w;
        if (lane == 15) stot = s;
    }
    __syncthreads();
    int local = ws[wid] + x - v;     // block-local exclusive
    if (threadIdx.x == 0) {
        int prev = 0;
        if (tile > 0) {
            int vv;
            while ((((vv = __hip_atomic_load(&st[tile - 1], __ATOMIC_ACQUIRE,
                                             __HIP_MEMORY_SCOPE_AGENT))) & SFLAG) == 0) {}
            prev = vv & ~SFLAG;
        }
        __hip_atomic_store(&st[tile], (prev + stot) | SFLAG, __ATOMIC_RELEASE,
                           __HIP_MEMORY_SCOPE_AGENT);
        sprev = prev;
        if (tile == nb - 1) offs[n] = prev + stot;
    }
    __syncthreads();
    if (i < n) offs[i] = sprev + local;
}

// ====== fused: CSR fill via rank (blocks >= EB) + embed+conv1-linear =========
__launch_bounds__(256)
__global__ void k_fill_embedlin(const int* __restrict__ srcArr, const int* __restrict__ dstArr,
                                int E, int N, const int* __restrict__ offs,
                                const int* __restrict__ rank, int* __restrict__ csr,
                                const void* __restrict__ xraw, const int* __restrict__ flag,
                                const float* __restrict__ aeW, const float* __restrict__ aeb,
                                const float* __restrict__ Wl, const float* __restrict__ bl,
                                const float* __restrict__ Wr, const float* __restrict__ br,
                                __half* __restrict__ outl, float* __restrict__ outr,
                                int EB) {
    __shared__ float xs[100 * 36];
    __shared__ float axs[32 * 36];
    if (blockIdx.x >= EB) {
        int e = (blockIdx.x - EB) * 256 + threadIdx.x;
        int EA = E + N;
        if (e >= EA) return;
        int d, s;
        if (e < E) { d = dstArr[e]; s = srcArr[e]; } else { d = s = e - E; }
        csr[offs[d] + rank[e]] = s;     // no atomics: rank captured during count
        return;
    }
    constexpr int NTP = 36;
    int t = threadIdx.x, nb = blockIdx.x * 32;
    if (flag[0]) {
        const float4* x4 = (const float4*)xraw;
        for (int idx = t; idx < 32 * 25; idx += 256) {
            int node = idx / 25, k4 = idx % 25;
            float4 v = x4[(size_t)(nb + node) * 25 + k4];
            xs[(k4 * 4 + 0) * NTP + node] = v.x;
            xs[(k4 * 4 + 1) * NTP + node] = v.y;
            xs[(k4 * 4 + 2) * NTP + node] = v.z;
            xs[(k4 * 4 + 3) * NTP + node] = v.w;
        }
    } else {
        const ushort4* xu = (const ushort4*)xraw;
        for (int idx = t; idx < 32 * 25; idx += 256) {
            int node = idx / 25, k4 = idx % 25;
            ushort4 u = xu[(size_t)(nb + node) * 25 + k4];
            xs[(k4 * 4 + 0) * NTP + node] = __uint_as_float((unsigned)u.x << 16);
            xs[(k4 * 4 + 1) * NTP + node] = __uint_as_float((unsigned)u.y << 16);
            xs[(k4 * 4 + 2) * NTP + node] = __uint_as_float((unsigned)u.z << 16);
            xs[(k4 * 4 + 3) * NTP + node] = __uint_as_float((unsigned)u.w << 16);
        }
    }
    __syncthreads();
    {
        int j = t & 31, g0 = t >> 5;
        float a0 = 0.f, a1 = 0.f, a2 = 0.f, a3 = 0.f;
        #pragma unroll 10
        for (int k = 0; k < 100; k++) {
            float w = aeW[k * 32 + j];
            const float4 xv = *(const float4*)&xs[k * NTP + g0 * 4];
            a0 += w * xv.x; a1 += w * xv.y; a2 += w * xv.z; a3 += w * xv.w;
        }
        float bj = aeb[j];
        axs[j * NTP + g0 * 4 + 0] = fmaxf(a0 + bj, 0.f);
        axs[j * NTP + g0 * 4 + 1] = fmaxf(a1 + bj, 0.f);
        axs[j * NTP + g0 * 4 + 2] = fmaxf(a2 + bj, 0.f);
        axs[j * NTP + g0 * 4 + 3] = fmaxf(a3 + bj, 0.f);
    }
    __syncthreads();
    {
        int j = t & 63, g0 = t >> 6;
        float aL0[2][4], aL1[2][4], aR0[2][4], aR1[2][4];
        #pragma unroll
        for (int g = 0; g < 2; g++)
            #pragma unroll
            for (int c = 0; c < 4; c++) { aL0[g][c]=0.f; aL1[g][c]=0.f; aR0[g][c]=0.f; aR1[g][c]=0.f; }
        #pragma unroll 4
        for (int k = 0; k < 32; k++) {
            float wl0 = Wl[k * 128 + j];
            float wl1 = Wl[k * 128 + j + 64];
            float wr0 = Wr[k * 128 + j];
            float wr1 = Wr[k * 128 + j + 64];
            #pragma unroll
            for (int g = 0; g < 2; g++) {
                const float4 xv = *(const float4*)&axs[k * NTP + (g0 + g * 4) * 4];
                aL0[g][0] += wl0 * xv.x; aL0[g][1] += wl0 * xv.y; aL0[g][2] += wl0 * xv.z; aL0[g][3] += wl0 * xv.w;
                aL1[g][0] += wl1 * xv.x; aL1[g][1] += wl1 * xv.y; aL1[g][2] += wl1 * xv.z; aL1[g][3] += wl1 * xv.w;
                aR0[g][0] += wr0 * xv.x; aR0[g][1] += wr0 * xv.y; aR0[g][2] += wr0 * xv.z; aR0[g][3] += wr0 * xv.w;
                aR1[g][0] += wr1 * xv.x; aR1[g][1] += wr1 * xv.y; aR1[g][2] += wr1 * xv.z; aR1[g][3] += wr1 * xv.w;
            }
        }
        float bl0 = bl[j], bl1 = bl[j + 64], br0 = br[j], br1 = br[j + 64];
        #pragma unroll
        for (int g = 0; g < 2; g++) {
            int n0 = nb + (g0 + g * 4) * 4;
            #pragma unroll
            for (int c = 0; c < 4; c++) {
                size_t row = (size_t)(n0 + c) * 128;
                outl[row + j]      = __float2half(aL0[g][c] + bl0);
                outl[row + j + 64] = __float2half(aL1[g][c] + bl1);
                outr[row + j]      = aR0[g][c] + br0;
                outr[row + j + 64] = aR1[g][c] + br1;
            }
        }
    }
}

// ===== dual linear FOUT=128, 2 W-cols/thread; xl->fp16, xr->fp32 =============
template <int FIN, int NT>
__launch_bounds__(256)
__global__ void k_lin2w(const float* __restrict__ x,
                        const float* __restrict__ Wl, const float* __restrict__ bl,
                        const float* __restrict__ Wr, const float* __restrict__ br,
                        __half* __restrict__ outl, float* __restrict__ outr) {
    constexpr int NTP = NT + 4;
    constexpr int GPT = (NT / 4) / 4;
    __shared__ float xs[FIN * NTP];
    int t = threadIdx.x, nb = blockIdx.x * NT;

    const float4* x4 = (const float4*)x;
    for (int idx = t; idx < NT * (FIN / 4); idx += 256) {
        int node = idx / (FIN / 4), k4 = idx % (FIN / 4);
        float4 v = x4[(size_t)(nb + node) * (FIN / 4) + k4];
        xs[(k4 * 4 + 0) * NTP + node] = v.x;
        xs[(k4 * 4 + 1) * NTP + node] = v.y;
        xs[(k4 * 4 + 2) * NTP + node] = v.z;
        xs[(k4 * 4 + 3) * NTP + node] = v.w;
    }
    __syncthreads();

    int j = t & 63, g0 = t >> 6;
    float aL0[GPT][4], aL1[GPT][4], aR0[GPT][4], aR1[GPT][4];
    #pragma unroll
    for (int g = 0; g < GPT; g++)
        #pragma unroll
        for (int c = 0; c < 4; c++) { aL0[g][c]=0.f; aL1[g][c]=0.f; aR0[g][c]=0.f; aR1[g][c]=0.f; }

    #pragma unroll 4
    for (int k = 0; k < FIN; k++) {
        float wl0 = Wl[(size_t)k * 128 + j];
        float wl1 = Wl[(size_t)k * 128 + j + 64];
        float wr0 = Wr[(size_t)k * 128 + j];
        float wr1 = Wr[(size_t)k * 128 + j + 64];
        #pragma unroll
        for (int g = 0; g < GPT; g++) {
            const float4 xv = *(const float4*)&xs[k * NTP + (g0 + g * 4) * 4];
            aL0[g][0] += wl0 * xv.x; aL0[g][1] += wl0 * xv.y; aL0[g][2] += wl0 * xv.z; aL0[g][3] += wl0 * xv.w;
            aL1[g][0] += wl1 * xv.x; aL1[g][1] += wl1 * xv.y; aL1[g][2] += wl1 * xv.z; aL1[g][3] += wl1 * xv.w;
            aR0[g][0] += wr0 * xv.x; aR0[g][1] += wr0 * xv.y; aR0[g][2] += wr0 * xv.z; aR0[g][3] += wr0 * xv.w;
            aR1[g][0] += wr1 * xv.x; aR1[g][1] += wr1 * xv.y; aR1[g][2] += wr1 * xv.z; aR1[g][3] += wr1 * xv.w;
        }
    }

    float bl0 = bl[j], bl1 = bl[j + 64], br0 = br[j], br1 = br[j + 64];
    #pragma unroll
    for (int g = 0; g < GPT; g++) {
        int n0 = nb + (g0 + g * 4) * 4;
        #pragma unroll
        for (int c = 0; c < 4; c++) {
            size_t row = (size_t)(n0 + c) * 128;
            outl[row + j]      = __float2half(aL0[g][c] + bl0);
            outl[row + j + 64] = __float2half(aL1[g][c] + bl1);
            outr[row + j]      = aR0[g][c] + br0;
            outr[row + j + 64] = aR1[g][c] + br1;
        }
    }
}

// ===== dual linear FIN=128, FOUT=32 (global layer); xl->fp16, xr->fp32 =======
__launch_bounds__(256)
__global__ void k_ling(const float* __restrict__ x,
                       const float* __restrict__ Wl, const float* __restrict__ bl,
                       const float* __restrict__ Wr, const float* __restrict__ br,
                       __half* __restrict__ outl, float* __restrict__ outr) {
    constexpr int NT = 32, NTP = 36, FIN = 128;
    __shared__ float xs[FIN * NTP];
    int t = threadIdx.x, nb = blockIdx.x * NT;

    const float4* x4 = (const float4*)x;
    for (int idx = t; idx < NT * 32; idx += 256) {
        int node = idx >> 5, k4 = idx & 31;
        float4 v = x4[(size_t)(nb + node) * 32 + k4];
        xs[(k4 * 4 + 0) * NTP + node] = v.x;
        xs[(k4 * 4 + 1) * NTP + node] = v.y;
        xs[(k4 * 4 + 2) * NTP + node] = v.z;
        xs[(k4 * 4 + 3) * NTP + node] = v.w;
    }
    __syncthreads();

    int j = t & 31, g0 = t >> 5;
    float aL[4], aR[4];
    #pragma unroll
    for (int c = 0; c < 4; c++) { aL[c] = 0.f; aR[c] = 0.f; }

    #pragma unroll 4
    for (int k = 0; k < FIN; k++) {
        float wl = Wl[(size_t)k * 32 + j];
        float wr = Wr[(size_t)k * 32 + j];
        const float4 xv = *(const float4*)&xs[k * NTP + g0 * 4];
        aL[0] += wl * xv.x; aL[1] += wl * xv.y; aL[2] += wl * xv.z; aL[3] += wl * xv.w;
        aR[0] += wr * xv.x; aR[1] += wr * xv.y; aR[2] += wr * xv.z; aR[3] += wr * xv.w;
    }

    float blj = bl[j], brj = br[j];
    #pragma unroll
    for (int c = 0; c < 4; c++) {
        size_t row = (size_t)(nb + g0 * 4 + c) * 32;
        outl[row + j] = __float2half(aL[c] + blj);
        outr[row + j] = aR[c] + brj;
    }
}

// ===== fused GAT H=4: wave/dst, csr in registers, 4 rows in flight ===========
__launch_bounds__(256)
__global__ void k_gat4h(const __half* __restrict__ xl, const float* __restrict__ xr,
                        const float* __restrict__ att,
                        const int* __restrict__ offs, const int* __restrict__ csr,
                        const float* __restrict__ bias, float* __restrict__ out,
                        int N) {
    int wave = threadIdx.x >> 6, lane = threadIdx.x & 63;
    int d = blockIdx.x * 4 + wave;
    if (d >= N) return;
    int grp = lane >> 4, sub = lane & 15;     // 4 edge-groups x 16 lanes
    int i0 = offs[d], i1 = offs[d + 1];

    float xrd[8], av[8], acc[8];
    {
        const float4* p4 = (const float4*)(xr + (size_t)d * 128 + sub * 8);
        float4 a = p4[0], b = p4[1];
        xrd[0]=a.x; xrd[1]=a.y; xrd[2]=a.z; xrd[3]=a.w;
        xrd[4]=b.x; xrd[5]=b.y; xrd[6]=b.z; xrd[7]=b.w;
        const float4* t4 = (const float4*)(att + sub * 8);
        float4 c = t4[0], e = t4[1];
        av[0]=c.x; av[1]=c.y; av[2]=c.z; av[3]=c.w;
        av[4]=e.x; av[5]=e.y; av[6]=e.z; av[7]=e.w;
    }
    #pragma unroll
    for (int c = 0; c < 8; c++) acc[c] = 0.f;
    float sm = 0.f;

    auto proc = [&](float4 raw) {
        const __half2* h = (const __half2*)&raw;
        float v[8];
        float2 f;
        f = __half22float2(h[0]); v[0] = f.x; v[1] = f.y;
        f = __half22float2(h[1]); v[2] = f.x; v[3] = f.y;
        f = __half22float2(h[2]); v[4] = f.x; v[5] = f.y;
        f = __half22float2(h[3]); v[6] = f.x; v[7] = f.y;
        float p = 0.f;
        #pragma unroll
        for (int c = 0; c < 8; c++) {
            float u = v[c] + xrd[c];
            u = (u > 0.f) ? u : NEG_SLOPE * u;
            p += u * av[c];
        }
        p += __shfl_xor(p, 1);
        p += __shfl_xor(p, 2);
        p += __shfl_xor(p, 4);
        p += __shfl_xor(p, 8);
        float w = __expf(fminf(p, 80.f));
        sm += w;
        #pragma unroll
        for (int c = 0; c < 8; c++) acc[c] += w * v[c];
    };

    for (int base = i0; base < i1; base += 64) {
        int cnt = min(i1 - base, 64);
        int myv = (lane < cnt) ? csr[base + lane] : 0;   // whole adjacency chunk, 1 load
        int m16 = cnt >> 4;
        for (int q = 0; q < m16; q++) {
            int b4 = q * 16 + grp;
            int s0 = __shfl(myv, b4);
            int s1 = __shfl(myv, b4 + 4);
            int s2 = __shfl(myv, b4 + 8);
            int s3 = __shfl(myv, b4 + 12);
            float4 r0 = *(const float4*)(xl + (size_t)s0 * 128 + sub * 8);
            float4 r1 = *(const float4*)(xl + (size_t)s1 * 128 + sub * 8);
            float4 r2 = *(const float4*)(xl + (size_t)s2 * 128 + sub * 8);
            float4 r3 = *(const float4*)(xl + (size_t)s3 * 128 + sub * 8);
            proc(r0); proc(r1); proc(r2); proc(r3);
        }
        for (int j = m16 * 16 + grp; j < cnt; j += 4) {
            int s = __shfl(myv, j);
            float4 r = *(const float4*)(xl + (size_t)s * 128 + sub * 8);
            proc(r);
        }
    }

    // merge 4 edge-groups
    sm += __shfl_xor(sm, 16); sm += __shfl_xor(sm, 32);
    #pragma unroll
    for (int c = 0; c < 8; c++) {
        acc[c] += __shfl_xor(acc[c], 16);
        acc[c] += __shfl_xor(acc[c], 32);
    }
    if (grp == 0) {
        float inv = 1.f / (sm + 1e-16f);
        const float4* b4p = (const float4*)(bias + sub * 8);
        float4 b0 = b4p[0], b1 = b4p[1];
        float4 o0, o1;
        o0.x = fmaxf(acc[0] * inv + b0.x, 0.f);
        o0.y = fmaxf(acc[1] * inv + b0.y, 0.f);
        o0.z = fmaxf(acc[2] * inv + b0.z, 0.f);
        o0.w = fmaxf(acc[3] * inv + b0.w, 0.f);
        o1.x = fmaxf(acc[4] * inv + b1.x, 0.f);
        o1.y = fmaxf(acc[5] * inv + b1.y, 0.f);
        o1.z = fmaxf(acc[6] * inv + b1.z, 0.f);
        o1.w = fmaxf(acc[7] * inv + b1.w, 0.f);
        float4* op = (float4*)(out + (size_t)d * 128 + sub * 8);
        op[0] = o0; op[1] = o1;
    }
}

// ===== tail: global-GAT gather for the 64 FOCAL dsts only + output head =====
__launch_bounds__(64)
__global__ void k_tailf(const __half* __restrict__ xl, const float* __restrict__ xr,
                        const float* __restrict__ att,
                        const int* __restrict__ offs, const int* __restrict__ csr,
                        const float* __restrict__ gb, const int* __restrict__ focal,
                        const float* __restrict__ clf, const float* __restrict__ clW,
                        const float* __restrict__ clb, const float* __restrict__ fcW,
                        const float* __restrict__ fcb, void* __restrict__ out,
                        const int* __restrict__ flag) {
    __shared__ float comb[64];
    __shared__ float ssb[2];
    int b = blockIdx.x;
    int t = threadIdx.x;                  // 64
    int d = focal[b];
    int grp = t >> 3, sub = t & 7;        // 8 edge-groups x 8 lanes (4 ch each)
    int i0 = offs[d], i1 = offs[d + 1];

    float xrd[4], av[4], acc[4];
    {
        float4 a = *(const float4*)(xr + (size_t)d * 32 + sub * 4);
        xrd[0]=a.x; xrd[1]=a.y; xrd[2]=a.z; xrd[3]=a.w;
        float4 c = *(const float4*)(att + sub * 4);
        av[0]=c.x; av[1]=c.y; av[2]=c.z; av[3]=c.w;
    }
    #pragma unroll
    for (int c = 0; c < 4; c++) acc[c] = 0.f;
    float sm = 0.f;

    for (int i = i0 + grp; i < i1; i += 8) {
        float2 raw = *(const float2*)(xl + (size_t)csr[i] * 32 + sub * 4);
        const __half2* h = (const __half2*)&raw;
        float v[4];
        float2 f;
        f = __half22float2(h[0]); v[0] = f.x; v[1] = f.y;
        f = __half22float2(h[1]); v[2] = f.x; v[3] = f.y;
        float p = 0.f;
        #pragma unroll
        for (int c = 0; c < 4; c++) {
            float u = v[c] + xrd[c];
            u = (u > 0.f) ? u : NEG_SLOPE * u;
            p += u * av[c];
        }
        p += __shfl_xor(p, 1);
        p += __shfl_xor(p, 2);
        p += __shfl_xor(p, 4);
        float w = __expf(fminf(p, 80.f));
        sm += w;
        #pragma unroll
        for (int c = 0; c < 4; c++) acc[c] += w * v[c];
    }
    // merge 8 edge-groups
    sm += __shfl_xor(sm, 8); sm += __shfl_xor(sm, 16); sm += __shfl_xor(sm, 32);
    #pragma unroll
    for (int c = 0; c < 4; c++) {
        acc[c] += __shfl_xor(acc[c], 8);
        acc[c] += __shfl_xor(acc[c], 16);
        acc[c] += __shfl_xor(acc[c], 32);
    }
    if (grp == 0) {
        float inv = 1.f / (sm + 1e-16f);
        #pragma unroll
        for (int c = 0; c < 4; c++)
            comb[sub * 4 + c] = fmaxf(acc[c] * inv + gb[sub * 4 + c], 0.f);
    }
    if (t < 2) {
        float s = 0.f;
        for (int l = 0; l < 50; l++) s += clf[(size_t)b * 100 + l * 2 + t];
        ssb[t] = s / 50.f;
    }
    __syncthreads();
    if (t < 32) comb[32 + t] = ssb[0] * clW[t] + ssb[1] * clW[32 + t] + clb[t];
    __syncthreads();
    if (t < 60) {
        float a2 = fcb[t];
        #pragma unroll 16
        for (int k = 0; k < 64; k++) a2 += comb[k] * fcW[k * 60 + t];
        if (flag[0]) ((float*)out)[b * 60 + t] = a2;
        else ((bf16*)out)[b * 60 + t] = __float2bfloat16(a2);
    }
}

extern "C" void kernel_launch(void* const* d_in, const int* in_sizes, int n_in,
                              void* d_out, int out_size, void* d_ws, size_t ws_size,
                              hipStream_t stream) {
    const int* edge  = (const int*)d_in[1];
    const int* focal = (const int*)d_in[5];

    const int N = in_sizes[0] / 100;   // 20000
    const int E = in_sizes[1] / 2;     // 320000
    const int B = in_sizes[5];         // 64
    const int EA = E + N;
    const int* srcArr = edge;
    const int* dstArr = edge + E;

    // ---- conversion table: weights + centerlines -> fp32 in ws (x stays raw)
    const int idxs[NSEG] = {7,8,9,10,11,12,13,14,15,16,17,18,19,20,
                            35,36,37,38,39,40,41,42,43,44, 6};
    float* base = (float*)d_ws;
    int* flag = (int*)base;            // base[0..15] reserved
    float* wf = base + 16;
    Tab tab;
    int off[NSEG];
    int o = 0;
    for (int i = 0; i < NSEG; i++) {
        tab.s[i].src = d_in[idxs[i]];
        tab.s[i].n   = in_sizes[idxs[i]];
        tab.s[i].off = o;
        off[i] = o;
        o += in_sizes[idxs[i]];
    }
    const float* aeW  = wf + off[0],  *aeb  = wf + off[1];
    const float* a1Wl = wf + off[2],  *a1bl = wf + off[3];
    const float* a1Wr = wf + off[4],  *a1br = wf + off[5];
    const float* a1att= wf + off[6],  *a1b  = wf + off[7];
    const float* a2Wl = wf + off[8],  *a2bl = wf + off[9];
    const float* a2Wr = wf + off[10], *a2br = wf + off[11];
    const float* a2att= wf + off[12], *a2b  = wf + off[13];
    const float* clW  = wf + off[14], *clb  = wf + off[15];
    const float* gWl  = wf + off[16], *gbl  = wf + off[17];
    const float* gWr  = wf + off[18], *gbr  = wf + off[19];
    const float* gatt = wf + off[20], *gb   = wf + off[21];
    const float* fcW  = wf + off[22], *fcb  = wf + off[23];
    const float* clf  = wf + off[24];

    // ---- remaining workspace (keep 16B alignment) ----
    float* p = wf + o + ((4 - (o & 3)) & 3);
    size_t N128 = (size_t)N * 128;
    __half* hxl = (__half*)p;       p += (size_t)N * 64;    // xl fp16 [N,128] (global: [N,32])
    float* fB  = p;                 p += N128;              // xr fp32 (global: xrg)
    float* fC  = p;                 p += N128;              // h / agent_features fp32
    int* deg    = (int*)p;          // [N]
    int* st     = deg + N;          // [32] scan lookback state
    int* offs   = st + 32;          // N+1
    int* rank   = offs + N + 1;     // EA
    int* csr    = rank + EA;        // EA (src node ids)

    const int NB = (N + 1023) / 1024;          // scan tiles (20)
    const int EB = N / 32;                     // embedlin blocks (625)
    const int FBLK = (EA + 255) / 256;         // fill blocks

    // ---- detect + zero deg/st ----
    k_detect_zero<<<64, 256, 0, stream>>>((const unsigned short*)d_in[0], flag, deg, N + 32);
    // ---- convert weights + degree count with rank capture ----
    k_convert<<<256, 256, 0, stream>>>(tab, wf, flag, dstArr, E, N, deg, rank);
    // ---- single-kernel lookback scan ----
    k_scanf<<<NB, 1024, 0, stream>>>(deg, offs, N, st, NB);
    // ---- CSR fill (rank trick) + fused embed+conv1-linear ----
    k_fill_embedlin<<<EB + FBLK, 256, 0, stream>>>(srcArr, dstArr, E, N, offs, rank, csr,
                                                   d_in[0], flag, aeW, aeb,
                                                   a1Wl, a1bl, a1Wr, a1br, hxl, fB, EB);
    // ---- conv1 gather ----
    k_gat4h<<<(N + 3) / 4, 256, 0, stream>>>(hxl, fB, a1att, offs, csr, a1b, fC, N);
    // ---- conv2 ----
    k_lin2w<128, 32><<<N / 32, 256, 0, stream>>>(fC, a2Wl, a2bl, a2Wr, a2br, hxl, fB);
    k_gat4h<<<(N + 3) / 4, 256, 0, stream>>>(hxl, fB, a2att, offs, csr, a2b, fC, N);
    // ---- global linear (xlg fp16 for all nodes, xrg fp32) ----
    k_ling<<<N / 32, 256, 0, stream>>>(fC, gWl, gbl, gWr, gbr, hxl, fB);
    // ---- tail: global gather for the 64 focal dsts + head (gatgh eliminated)
    k_tailf<<<B, 64, 0, stream>>>(hxl, fB, gatt, offs, csr, gb, focal,
                                  clf, clW, clb, fcW, fcb, d_out, flag);
}

// Round 12
// 306.083 us; speedup vs baseline: 5.9721x; 1.0020x over previous
//
#include <hip/hip_runtime.h>
#include <hip/hip_bf16.h>
#include <hip/hip_fp16.h>
#include <math.h>

typedef __hip_bfloat16 bf16;
#define NEG_SLOPE 0.2f
#define SFLAG (1 << 30)

// ====== dtype detect (block 0) + zero deg/scan-state =========================
__global__ void k_detect_zero(const unsigned short* __restrict__ x, int* __restrict__ flag,
                              int* __restrict__ zbase, int n) {
    for (int i = blockIdx.x * blockDim.x + threadIdx.x; i < n; i += gridDim.x * blockDim.x)
        zbase[i] = 0;
    if (blockIdx.x == 0) {
        __shared__ int cnt;
        if (threadIdx.x == 0) cnt = 0;
        __syncthreads();
        int local = 0;
        for (int i = threadIdx.x; i < 2048; i += blockDim.x) {
            unsigned short w = x[2 * i];
            int e = (w >> 7) & 0xFF;
            if (e >= 0x90) local++;
        }
        atomicAdd(&cnt, local);
        __syncthreads();
        if (threadIdx.x == 0) flag[0] = (cnt > 100) ? 1 : 0;  // 1 => inputs are f32
    }
}

#define NSEG 25
struct Seg { const void* src; int n; int off; };
struct Tab { Seg s[NSEG]; };

// ====== convert weights to fp32 + degree count with rank capture =============
__global__ void k_convert(Tab tab, float* __restrict__ dst, const int* __restrict__ flag,
                          const int* __restrict__ dstArr, int E, int N,
                          int* __restrict__ deg, int* __restrict__ rank) {
    int f32mode = flag[0];
    int gid = blockIdx.x * blockDim.x + threadIdx.x;
    int gsz = gridDim.x * blockDim.x;
    for (int s = 0; s < NSEG; s++) {
        Seg sg = tab.s[s];
        for (int i = gid; i < sg.n; i += gsz) {
            float v = f32mode ? ((const float*)sg.src)[i]
                              : __bfloat162float(((const bf16*)sg.src)[i]);
            dst[sg.off + i] = v;
        }
    }
    int EA = E + N;
    for (int e = gid; e < EA; e += gsz) {
        int d = (e < E) ? dstArr[e] : (e - E);
        rank[e] = atomicAdd(&deg[d], 1);
    }
}

// ====== single-kernel chained-lookback exclusive scan ========================
__launch_bounds__(1024)
__global__ void k_scanf(const int* __restrict__ deg, int* __restrict__ offs,
                        int n, int* __restrict__ st, int nb) {
    __shared__ int ws[16];
    __shared__ int stot, sprev;
    int tile = blockIdx.x;
    int i = tile * 1024 + threadIdx.x;
    int lane = threadIdx.x & 63, wid = threadIdx.x >> 6;
    int v = (i < n) ? deg[i] : 0;
    int x = v;
    #pragma unroll
    for (int o = 1; o < 64; o <<= 1) {
        int y = __shfl_up(x, o);
        if (lane >= o) x += y;
    }
    if (lane == 63) ws[wid] = x;
    __syncthreads();
    if (wid == 0) {
        int w = (lane < 16) ? ws[lane] : 0;
        int s = w;
        #pragma unroll
        for (int o = 1; o < 16; o <<= 1) {
            int y = __shfl_up(s, o);
            if (lane >= o) s += y;
        }
        if (lane < 16) ws[lane] = s - w;
        if (lane == 15) stot = s;
    }
    __syncthreads();
    int local = ws[wid] + x - v;     // block-local exclusive
    if (threadIdx.x == 0) {
        int prev = 0;
        if (tile > 0) {
            int vv;
            while ((((vv = __hip_atomic_load(&st[tile - 1], __ATOMIC_ACQUIRE,
                                             __HIP_MEMORY_SCOPE_AGENT))) & SFLAG) == 0) {}
            prev = vv & ~SFLAG;
        }
        __hip_atomic_store(&st[tile], (prev + stot) | SFLAG, __ATOMIC_RELEASE,
                           __HIP_MEMORY_SCOPE_AGENT);
        sprev = prev;
        if (tile == nb - 1) offs[n] = prev + stot;
    }
    __syncthreads();
    if (i < n) offs[i] = sprev + local;
}

// ====== fused: CSR fill via rank (blocks >= EB) + embed+conv1-linear =========
__launch_bounds__(256)
__global__ void k_fill_embedlin(const int* __restrict__ srcArr, const int* __restrict__ dstArr,
                                int E, int N, const int* __restrict__ offs,
                                const int* __restrict__ rank, int* __restrict__ csr,
                                const void* __restrict__ xraw, const int* __restrict__ flag,
                                const float* __restrict__ aeW, const float* __restrict__ aeb,
                                const float* __restrict__ Wl, const float* __restrict__ bl,
                                const float* __restrict__ Wr, const float* __restrict__ br,
                                __half* __restrict__ outl, float* __restrict__ outr,
                                int EB) {
    __shared__ float xs[100 * 36];
    __shared__ float axs[32 * 36];
    if (blockIdx.x >= EB) {
        int e = (blockIdx.x - EB) * 256 + threadIdx.x;
        int EA = E + N;
        if (e >= EA) return;
        int d, s;
        if (e < E) { d = dstArr[e]; s = srcArr[e]; } else { d = s = e - E; }
        csr[offs[d] + rank[e]] = s;     // no atomics: rank captured during count
        return;
    }
    constexpr int NTP = 36;
    int t = threadIdx.x, nb = blockIdx.x * 32;
    if (flag[0]) {
        const float4* x4 = (const float4*)xraw;
        for (int idx = t; idx < 32 * 25; idx += 256) {
            int node = idx / 25, k4 = idx % 25;
            float4 v = x4[(size_t)(nb + node) * 25 + k4];
            xs[(k4 * 4 + 0) * NTP + node] = v.x;
            xs[(k4 * 4 + 1) * NTP + node] = v.y;
            xs[(k4 * 4 + 2) * NTP + node] = v.z;
            xs[(k4 * 4 + 3) * NTP + node] = v.w;
        }
    } else {
        const ushort4* xu = (const ushort4*)xraw;
        for (int idx = t; idx < 32 * 25; idx += 256) {
            int node = idx / 25, k4 = idx % 25;
            ushort4 u = xu[(size_t)(nb + node) * 25 + k4];
            xs[(k4 * 4 + 0) * NTP + node] = __uint_as_float((unsigned)u.x << 16);
            xs[(k4 * 4 + 1) * NTP + node] = __uint_as_float((unsigned)u.y << 16);
            xs[(k4 * 4 + 2) * NTP + node] = __uint_as_float((unsigned)u.z << 16);
            xs[(k4 * 4 + 3) * NTP + node] = __uint_as_float((unsigned)u.w << 16);
        }
    }
    __syncthreads();
    {
        int j = t & 31, g0 = t >> 5;
        float a0 = 0.f, a1 = 0.f, a2 = 0.f, a3 = 0.f;
        #pragma unroll 10
        for (int k = 0; k < 100; k++) {
            float w = aeW[k * 32 + j];
            const float4 xv = *(const float4*)&xs[k * NTP + g0 * 4];
            a0 += w * xv.x; a1 += w * xv.y; a2 += w * xv.z; a3 += w * xv.w;
        }
        float bj = aeb[j];
        axs[j * NTP + g0 * 4 + 0] = fmaxf(a0 + bj, 0.f);
        axs[j * NTP + g0 * 4 + 1] = fmaxf(a1 + bj, 0.f);
        axs[j * NTP + g0 * 4 + 2] = fmaxf(a2 + bj, 0.f);
        axs[j * NTP + g0 * 4 + 3] = fmaxf(a3 + bj, 0.f);
    }
    __syncthreads();
    {
        int j = t & 63, g0 = t >> 6;
        float aL0[2][4], aL1[2][4], aR0[2][4], aR1[2][4];
        #pragma unroll
        for (int g = 0; g < 2; g++)
            #pragma unroll
            for (int c = 0; c < 4; c++) { aL0[g][c]=0.f; aL1[g][c]=0.f; aR0[g][c]=0.f; aR1[g][c]=0.f; }
        #pragma unroll 4
        for (int k = 0; k < 32; k++) {
            float wl0 = Wl[k * 128 + j];
            float wl1 = Wl[k * 128 + j + 64];
            float wr0 = Wr[k * 128 + j];
            float wr1 = Wr[k * 128 + j + 64];
            #pragma unroll
            for (int g = 0; g < 2; g++) {
                const float4 xv = *(const float4*)&axs[k * NTP + (g0 + g * 4) * 4];
                aL0[g][0] += wl0 * xv.x; aL0[g][1] += wl0 * xv.y; aL0[g][2] += wl0 * xv.z; aL0[g][3] += wl0 * xv.w;
                aL1[g][0] += wl1 * xv.x; aL1[g][1] += wl1 * xv.y; aL1[g][2] += wl1 * xv.z; aL1[g][3] += wl1 * xv.w;
                aR0[g][0] += wr0 * xv.x; aR0[g][1] += wr0 * xv.y; aR0[g][2] += wr0 * xv.z; aR0[g][3] += wr0 * xv.w;
                aR1[g][0] += wr1 * xv.x; aR1[g][1] += wr1 * xv.y; aR1[g][2] += wr1 * xv.z; aR1[g][3] += wr1 * xv.w;
            }
        }
        float bl0 = bl[j], bl1 = bl[j + 64], br0 = br[j], br1 = br[j + 64];
        #pragma unroll
        for (int g = 0; g < 2; g++) {
            int n0 = nb + (g0 + g * 4) * 4;
            #pragma unroll
            for (int c = 0; c < 4; c++) {
                size_t row = (size_t)(n0 + c) * 128;
                outl[row + j]      = __float2half(aL0[g][c] + bl0);
                outl[row + j + 64] = __float2half(aL1[g][c] + bl1);
                outr[row + j]      = aR0[g][c] + br0;
                outr[row + j + 64] = aR1[g][c] + br1;
            }
        }
    }
}

// ====== shared device body: GAT H=4 gather of a 16-dst tile into LDS =========
// xs layout: xs[c * 20 + node], c in [0,128), node in [0,16). 10.24 KB.
__device__ __forceinline__ void gat16_to_lds(float* xs,
                                             const __half* __restrict__ xl,
                                             const float* __restrict__ xr,
                                             const float* __restrict__ att,
                                             const int* __restrict__ offs,
                                             const int* __restrict__ csr,
                                             const float* __restrict__ bias,
                                             int nb, int N) {
    int t = threadIdx.x;
    int wave = t >> 6, lane = t & 63;
    int grp = lane >> 4, sub = lane & 15;     // 4 edge-groups x 16 lanes
    float av[8];
    {
        const float4* t4 = (const float4*)(att + sub * 8);
        float4 c = t4[0], e = t4[1];
        av[0]=c.x; av[1]=c.y; av[2]=c.z; av[3]=c.w;
        av[4]=e.x; av[5]=e.y; av[6]=e.z; av[7]=e.w;
    }
    for (int it = 0; it < 4; it++) {
        int d = nb + wave * 4 + it;
        if (d >= N) break;
        int i0 = offs[d], i1 = offs[d + 1];
        float xrd[8], acc[8];
        {
            const float4* p4 = (const float4*)(xr + (size_t)d * 128 + sub * 8);
            float4 a = p4[0], b = p4[1];
            xrd[0]=a.x; xrd[1]=a.y; xrd[2]=a.z; xrd[3]=a.w;
            xrd[4]=b.x; xrd[5]=b.y; xrd[6]=b.z; xrd[7]=b.w;
        }
        #pragma unroll
        for (int c = 0; c < 8; c++) acc[c] = 0.f;
        float sm = 0.f;

        auto proc = [&](float4 raw) {
            const __half2* h = (const __half2*)&raw;
            float v[8];
            float2 f;
            f = __half22float2(h[0]); v[0] = f.x; v[1] = f.y;
            f = __half22float2(h[1]); v[2] = f.x; v[3] = f.y;
            f = __half22float2(h[2]); v[4] = f.x; v[5] = f.y;
            f = __half22float2(h[3]); v[6] = f.x; v[7] = f.y;
            float p = 0.f;
            #pragma unroll
            for (int c = 0; c < 8; c++) {
                float u = v[c] + xrd[c];
                u = (u > 0.f) ? u : NEG_SLOPE * u;
                p += u * av[c];
            }
            p += __shfl_xor(p, 1);
            p += __shfl_xor(p, 2);
            p += __shfl_xor(p, 4);
            p += __shfl_xor(p, 8);
            float w = __expf(fminf(p, 80.f));
            sm += w;
            #pragma unroll
            for (int c = 0; c < 8; c++) acc[c] += w * v[c];
        };

        for (int base = i0; base < i1; base += 64) {
            int cnt = min(i1 - base, 64);
            int myv = (lane < cnt) ? csr[base + lane] : 0;
            int m16 = cnt >> 4;
            for (int q = 0; q < m16; q++) {
                int b4 = q * 16 + grp;
                int s0 = __shfl(myv, b4);
                int s1 = __shfl(myv, b4 + 4);
                int s2 = __shfl(myv, b4 + 8);
                int s3 = __shfl(myv, b4 + 12);
                float4 r0 = *(const float4*)(xl + (size_t)s0 * 128 + sub * 8);
                float4 r1 = *(const float4*)(xl + (size_t)s1 * 128 + sub * 8);
                float4 r2 = *(const float4*)(xl + (size_t)s2 * 128 + sub * 8);
                float4 r3 = *(const float4*)(xl + (size_t)s3 * 128 + sub * 8);
                proc(r0); proc(r1); proc(r2); proc(r3);
            }
            for (int j = m16 * 16 + grp; j < cnt; j += 4) {
                int s = __shfl(myv, j);
                float4 r = *(const float4*)(xl + (size_t)s * 128 + sub * 8);
                proc(r);
            }
        }

        sm += __shfl_xor(sm, 16); sm += __shfl_xor(sm, 32);
        #pragma unroll
        for (int c = 0; c < 8; c++) {
            acc[c] += __shfl_xor(acc[c], 16);
            acc[c] += __shfl_xor(acc[c], 32);
        }
        if (grp == 0) {
            float inv = 1.f / (sm + 1e-16f);
            int node = d - nb;
            #pragma unroll
            for (int c = 0; c < 8; c++) {
                float o = fmaxf(acc[c] * inv + bias[sub * 8 + c], 0.f);
                xs[(sub * 8 + c) * 20 + node] = o;
            }
        }
    }
}

// ====== fused: conv1 gather (16-dst tile) -> conv2 dual linear ===============
__launch_bounds__(256)
__global__ void k_gatlin(const __half* __restrict__ xl, const float* __restrict__ xr,
                         const float* __restrict__ att,
                         const int* __restrict__ offs, const int* __restrict__ csr,
                         const float* __restrict__ bias,
                         const float* __restrict__ Wl, const float* __restrict__ bl,
                         const float* __restrict__ Wr, const float* __restrict__ br,
                         __half* __restrict__ outl, float* __restrict__ outr, int N) {
    __shared__ float xs[128 * 20];
    int nb = blockIdx.x * 16;
    gat16_to_lds(xs, xl, xr, att, offs, csr, bias, nb, N);
    __syncthreads();

    // conv2 dual linear, 16 nodes from LDS: j=t&63 (cols j, j+64), g0=t>>6 (4 node-groups x 4)
    int t = threadIdx.x;
    int j = t & 63, g0 = t >> 6;
    float aL0[4], aL1[4], aR0[4], aR1[4];
    #pragma unroll
    for (int c = 0; c < 4; c++) { aL0[c]=0.f; aL1[c]=0.f; aR0[c]=0.f; aR1[c]=0.f; }

    #pragma unroll 4
    for (int k = 0; k < 128; k++) {
        float wl0 = Wl[(size_t)k * 128 + j];
        float wl1 = Wl[(size_t)k * 128 + j + 64];
        float wr0 = Wr[(size_t)k * 128 + j];
        float wr1 = Wr[(size_t)k * 128 + j + 64];
        const float4 xv = *(const float4*)&xs[k * 20 + g0 * 4];
        aL0[0] += wl0 * xv.x; aL0[1] += wl0 * xv.y; aL0[2] += wl0 * xv.z; aL0[3] += wl0 * xv.w;
        aL1[0] += wl1 * xv.x; aL1[1] += wl1 * xv.y; aL1[2] += wl1 * xv.z; aL1[3] += wl1 * xv.w;
        aR0[0] += wr0 * xv.x; aR0[1] += wr0 * xv.y; aR0[2] += wr0 * xv.z; aR0[3] += wr0 * xv.w;
        aR1[0] += wr1 * xv.x; aR1[1] += wr1 * xv.y; aR1[2] += wr1 * xv.z; aR1[3] += wr1 * xv.w;
    }

    float bl0 = bl[j], bl1 = bl[j + 64], br0 = br[j], br1 = br[j + 64];
    #pragma unroll
    for (int c = 0; c < 4; c++) {
        int node = g0 * 4 + c;
        if (nb + node >= N) break;
        size_t row = (size_t)(nb + node) * 128;
        outl[row + j]      = __float2half(aL0[c] + bl0);
        outl[row + j + 64] = __float2half(aL1[c] + bl1);
        outr[row + j]      = aR0[c] + br0;
        outr[row + j + 64] = aR1[c] + br1;
    }
}

// ====== fused: conv2 gather (16-dst tile) -> global dual linear (FOUT=32) ====
__launch_bounds__(256)
__global__ void k_gatling(const __half* __restrict__ xl, const float* __restrict__ xr,
                          const float* __restrict__ att,
                          const int* __restrict__ offs, const int* __restrict__ csr,
                          const float* __restrict__ bias,
                          const float* __restrict__ Wl, const float* __restrict__ bl,
                          const float* __restrict__ Wr, const float* __restrict__ br,
                          __half* __restrict__ outl, float* __restrict__ outr, int N) {
    __shared__ float xs[128 * 20];
    int nb = blockIdx.x * 16;
    gat16_to_lds(xs, xl, xr, att, offs, csr, bias, nb, N);
    __syncthreads();

    // global dual linear FOUT=32, 16 nodes: j=t&31, g0=t>>5 (8 node-groups x 2)
    int t = threadIdx.x;
    int j = t & 31, g0 = t >> 5;
    float aL[2], aR[2];
    aL[0]=0.f; aL[1]=0.f; aR[0]=0.f; aR[1]=0.f;

    #pragma unroll 4
    for (int k = 0; k < 128; k++) {
        float wl = Wl[(size_t)k * 32 + j];
        float wr = Wr[(size_t)k * 32 + j];
        const float2 xv = *(const float2*)&xs[k * 20 + g0 * 2];
        aL[0] += wl * xv.x; aL[1] += wl * xv.y;
        aR[0] += wr * xv.x; aR[1] += wr * xv.y;
    }

    float blj = bl[j], brj = br[j];
    #pragma unroll
    for (int c = 0; c < 2; c++) {
        int node = g0 * 2 + c;
        if (nb + node >= N) break;
        size_t row = (size_t)(nb + node) * 32;
        outl[row + j] = __float2half(aL[c] + blj);
        outr[row + j] = aR[c] + brj;
    }
}

// ===== tail: global-GAT gather for the 64 FOCAL dsts only + output head =====
__launch_bounds__(64)
__global__ void k_tailf(const __half* __restrict__ xl, const float* __restrict__ xr,
                        const float* __restrict__ att,
                        const int* __restrict__ offs, const int* __restrict__ csr,
                        const float* __restrict__ gb, const int* __restrict__ focal,
                        const float* __restrict__ clf, const float* __restrict__ clW,
                        const float* __restrict__ clb, const float* __restrict__ fcW,
                        const float* __restrict__ fcb, void* __restrict__ out,
                        const int* __restrict__ flag) {
    __shared__ float comb[64];
    __shared__ float ssb[2];
    int b = blockIdx.x;
    int t = threadIdx.x;                  // 64
    int d = focal[b];
    int grp = t >> 3, sub = t & 7;        // 8 edge-groups x 8 lanes (4 ch each)
    int i0 = offs[d], i1 = offs[d + 1];

    float xrd[4], av[4], acc[4];
    {
        float4 a = *(const float4*)(xr + (size_t)d * 32 + sub * 4);
        xrd[0]=a.x; xrd[1]=a.y; xrd[2]=a.z; xrd[3]=a.w;
        float4 c = *(const float4*)(att + sub * 4);
        av[0]=c.x; av[1]=c.y; av[2]=c.z; av[3]=c.w;
    }
    #pragma unroll
    for (int c = 0; c < 4; c++) acc[c] = 0.f;
    float sm = 0.f;

    for (int i = i0 + grp; i < i1; i += 8) {
        float2 raw = *(const float2*)(xl + (size_t)csr[i] * 32 + sub * 4);
        const __half2* h = (const __half2*)&raw;
        float v[4];
        float2 f;
        f = __half22float2(h[0]); v[0] = f.x; v[1] = f.y;
        f = __half22float2(h[1]); v[2] = f.x; v[3] = f.y;
        float p = 0.f;
        #pragma unroll
        for (int c = 0; c < 4; c++) {
            float u = v[c] + xrd[c];
            u = (u > 0.f) ? u : NEG_SLOPE * u;
            p += u * av[c];
        }
        p += __shfl_xor(p, 1);
        p += __shfl_xor(p, 2);
        p += __shfl_xor(p, 4);
        float w = __expf(fminf(p, 80.f));
        sm += w;
        #pragma unroll
        for (int c = 0; c < 4; c++) acc[c] += w * v[c];
    }
    // merge 8 edge-groups
    sm += __shfl_xor(sm, 8); sm += __shfl_xor(sm, 16); sm += __shfl_xor(sm, 32);
    #pragma unroll
    for (int c = 0; c < 4; c++) {
        acc[c] += __shfl_xor(acc[c], 8);
        acc[c] += __shfl_xor(acc[c], 16);
        acc[c] += __shfl_xor(acc[c], 32);
    }
    if (grp == 0) {
        float inv = 1.f / (sm + 1e-16f);
        #pragma unroll
        for (int c = 0; c < 4; c++)
            comb[sub * 4 + c] = fmaxf(acc[c] * inv + gb[sub * 4 + c], 0.f);
    }
    if (t < 2) {
        float s = 0.f;
        for (int l = 0; l < 50; l++) s += clf[(size_t)b * 100 + l * 2 + t];
        ssb[t] = s / 50.f;
    }
    __syncthreads();
    if (t < 32) comb[32 + t] = ssb[0] * clW[t] + ssb[1] * clW[32 + t] + clb[t];
    __syncthreads();
    if (t < 60) {
        float a2 = fcb[t];
        #pragma unroll 16
        for (int k = 0; k < 64; k++) a2 += comb[k] * fcW[k * 60 + t];
        if (flag[0]) ((float*)out)[b * 60 + t] = a2;
        else ((bf16*)out)[b * 60 + t] = __float2bfloat16(a2);
    }
}

extern "C" void kernel_launch(void* const* d_in, const int* in_sizes, int n_in,
                              void* d_out, int out_size, void* d_ws, size_t ws_size,
                              hipStream_t stream) {
    const int* edge  = (const int*)d_in[1];
    const int* focal = (const int*)d_in[5];

    const int N = in_sizes[0] / 100;   // 20000
    const int E = in_sizes[1] / 2;     // 320000
    const int B = in_sizes[5];         // 64
    const int EA = E + N;
    const int* srcArr = edge;
    const int* dstArr = edge + E;

    // ---- conversion table: weights + centerlines -> fp32 in ws (x stays raw)
    const int idxs[NSEG] = {7,8,9,10,11,12,13,14,15,16,17,18,19,20,
                            35,36,37,38,39,40,41,42,43,44, 6};
    float* base = (float*)d_ws;
    int* flag = (int*)base;            // base[0..15] reserved
    float* wf = base + 16;
    Tab tab;
    int off[NSEG];
    int o = 0;
    for (int i = 0; i < NSEG; i++) {
        tab.s[i].src = d_in[idxs[i]];
        tab.s[i].n   = in_sizes[idxs[i]];
        tab.s[i].off = o;
        off[i] = o;
        o += in_sizes[idxs[i]];
    }
    const float* aeW  = wf + off[0],  *aeb  = wf + off[1];
    const float* a1Wl = wf + off[2],  *a1bl = wf + off[3];
    const float* a1Wr = wf + off[4],  *a1br = wf + off[5];
    const float* a1att= wf + off[6],  *a1b  = wf + off[7];
    const float* a2Wl = wf + off[8],  *a2bl = wf + off[9];
    const float* a2Wr = wf + off[10], *a2br = wf + off[11];
    const float* a2att= wf + off[12], *a2b  = wf + off[13];
    const float* clW  = wf + off[14], *clb  = wf + off[15];
    const float* gWl  = wf + off[16], *gbl  = wf + off[17];
    const float* gWr  = wf + off[18], *gbr  = wf + off[19];
    const float* gatt = wf + off[20], *gb   = wf + off[21];
    const float* fcW  = wf + off[22], *fcb  = wf + off[23];
    const float* clf  = wf + off[24];

    // ---- remaining workspace (keep 16B alignment) ----
    float* p = wf + o + ((4 - (o & 3)) & 3);
    size_t N128 = (size_t)N * 128;
    __half* hxl1 = (__half*)p;      p += (size_t)N * 64;    // conv1 xl fp16 [N,128]; later global xl [N,32]
    float* fB1  = p;                p += N128;              // conv1 xr fp32; later global xrg [N,32]
    __half* hxl2 = (__half*)p;      p += (size_t)N * 64;    // conv2 xl fp16 [N,128]
    float* fB2  = p;                p += N128;              // conv2 xr fp32
    int* deg    = (int*)p;          // [N]
    int* st     = deg + N;          // [32] scan lookback state
    int* offs   = st + 32;          // N+1
    int* rank   = offs + N + 1;     // EA
    int* csr    = rank + EA;        // EA (src node ids)

    const int NB = (N + 1023) / 1024;          // scan tiles (20)
    const int EB = N / 32;                     // embedlin blocks (625)
    const int FBLK = (EA + 255) / 256;         // fill blocks
    const int GT = (N + 15) / 16;              // fused gather+linear tiles (1250)

    // ---- detect + zero deg/st ----
    k_detect_zero<<<64, 256, 0, stream>>>((const unsigned short*)d_in[0], flag, deg, N + 32);
    // ---- convert weights + degree count with rank capture ----
    k_convert<<<256, 256, 0, stream>>>(tab, wf, flag, dstArr, E, N, deg, rank);
    // ---- single-kernel lookback scan ----
    k_scanf<<<NB, 1024, 0, stream>>>(deg, offs, N, st, NB);
    // ---- CSR fill (rank trick) + fused embed+conv1-linear -> hxl1/fB1 ----
    k_fill_embedlin<<<EB + FBLK, 256, 0, stream>>>(srcArr, dstArr, E, N, offs, rank, csr,
                                                   d_in[0], flag, aeW, aeb,
                                                   a1Wl, a1bl, a1Wr, a1br, hxl1, fB1, EB);
    // ---- conv1 gather + conv2 linear (fC stays in LDS) -> hxl2/fB2 ----
    k_gatlin<<<GT, 256, 0, stream>>>(hxl1, fB1, a1att, offs, csr, a1b,
                                     a2Wl, a2bl, a2Wr, a2br, hxl2, fB2, N);
    // ---- conv2 gather + global linear -> hxl1([N,32]) / fB1([N,32]) ----
    k_gatling<<<GT, 256, 0, stream>>>(hxl2, fB2, a2att, offs, csr, a2b,
                                      gWl, gbl, gWr, gbr, hxl1, fB1, N);
    // ---- tail: global gather for the 64 focal dsts + head ----
    k_tailf<<<B, 64, 0, stream>>>(hxl1, fB1, gatt, offs, csr, gb, focal,
                                  clf, clW, clb, fcW, fcb, d_out, flag);
}

// Round 13
// 301.081 us; speedup vs baseline: 6.0713x; 1.0166x over previous
//
#include <hip/hip_runtime.h>
#include <hip/hip_bf16.h>
#include <hip/hip_fp16.h>
#include <math.h>

typedef __hip_bfloat16 bf16;
#define NEG_SLOPE 0.2f
#define SFLAG (1 << 30)

// ====== dtype detect (block 0) + zero deg/scan-state =========================
__global__ void k_detect_zero(const unsigned short* __restrict__ x, int* __restrict__ flag,
                              int* __restrict__ zbase, int n) {
    for (int i = blockIdx.x * blockDim.x + threadIdx.x; i < n; i += gridDim.x * blockDim.x)
        zbase[i] = 0;
    if (blockIdx.x == 0) {
        __shared__ int cnt;
        if (threadIdx.x == 0) cnt = 0;
        __syncthreads();
        int local = 0;
        for (int i = threadIdx.x; i < 2048; i += blockDim.x) {
            unsigned short w = x[2 * i];
            int e = (w >> 7) & 0xFF;
            if (e >= 0x90) local++;
        }
        atomicAdd(&cnt, local);
        __syncthreads();
        if (threadIdx.x == 0) flag[0] = (cnt > 100) ? 1 : 0;  // 1 => inputs are f32
    }
}

#define NSEG 25
struct Seg { const void* src; int n; int off; };
struct Tab { Seg s[NSEG]; };

// ====== convert weights to fp32 + degree count with rank capture =============
__global__ void k_convert(Tab tab, float* __restrict__ dst, const int* __restrict__ flag,
                          const int* __restrict__ dstArr, int E, int N,
                          int* __restrict__ deg, int* __restrict__ rank) {
    int f32mode = flag[0];
    int gid = blockIdx.x * blockDim.x + threadIdx.x;
    int gsz = gridDim.x * blockDim.x;
    for (int s = 0; s < NSEG; s++) {
        Seg sg = tab.s[s];
        for (int i = gid; i < sg.n; i += gsz) {
            float v = f32mode ? ((const float*)sg.src)[i]
                              : __bfloat162float(((const bf16*)sg.src)[i]);
            dst[sg.off + i] = v;
        }
    }
    int EA = E + N;
    for (int e = gid; e < EA; e += gsz) {
        int d = (e < E) ? dstArr[e] : (e - E);
        rank[e] = atomicAdd(&deg[d], 1);
    }
}

// ====== single-kernel chained-lookback exclusive scan ========================
__launch_bounds__(1024)
__global__ void k_scanf(const int* __restrict__ deg, int* __restrict__ offs,
                        int n, int* __restrict__ st, int nb) {
    __shared__ int ws[16];
    __shared__ int stot, sprev;
    int tile = blockIdx.x;
    int i = tile * 1024 + threadIdx.x;
    int lane = threadIdx.x & 63, wid = threadIdx.x >> 6;
    int v = (i < n) ? deg[i] : 0;
    int x = v;
    #pragma unroll
    for (int o = 1; o < 64; o <<= 1) {
        int y = __shfl_up(x, o);
        if (lane >= o) x += y;
    }
    if (lane == 63) ws[wid] = x;
    __syncthreads();
    if (wid == 0) {
        int w = (lane < 16) ? ws[lane] : 0;
        int s = w;
        #pragma unroll
        for (int o = 1; o < 16; o <<= 1) {
            int y = __shfl_up(s, o);
            if (lane >= o) s += y;
        }
        if (lane < 16) ws[lane] = s - w;
        if (lane == 15) stot = s;
    }
    __syncthreads();
    int local = ws[wid] + x - v;     // block-local exclusive
    if (threadIdx.x == 0) {
        int prev = 0;
        if (tile > 0) {
            int vv;
            while ((((vv = __hip_atomic_load(&st[tile - 1], __ATOMIC_ACQUIRE,
                                             __HIP_MEMORY_SCOPE_AGENT))) & SFLAG) == 0) {}
            prev = vv & ~SFLAG;
        }
        __hip_atomic_store(&st[tile], (prev + stot) | SFLAG, __ATOMIC_RELEASE,
                           __HIP_MEMORY_SCOPE_AGENT);
        sprev = prev;
        if (tile == nb - 1) offs[n] = prev + stot;
    }
    __syncthreads();
    if (i < n) offs[i] = sprev + local;
}

// ====== fused: CSR fill via rank (blocks >= EB) + embed+conv1-linear =========
__launch_bounds__(256)
__global__ void k_fill_embedlin(const int* __restrict__ srcArr, const int* __restrict__ dstArr,
                                int E, int N, const int* __restrict__ offs,
                                const int* __restrict__ rank, int* __restrict__ csr,
                                const void* __restrict__ xraw, const int* __restrict__ flag,
                                const float* __restrict__ aeW, const float* __restrict__ aeb,
                                const float* __restrict__ Wl, const float* __restrict__ bl,
                                const float* __restrict__ Wr, const float* __restrict__ br,
                                __half* __restrict__ outl, float* __restrict__ outr,
                                int EB) {
    __shared__ float xs[100 * 36];
    __shared__ float axs[32 * 36];
    if (blockIdx.x >= EB) {
        int e = (blockIdx.x - EB) * 256 + threadIdx.x;
        int EA = E + N;
        if (e >= EA) return;
        int d, s;
        if (e < E) { d = dstArr[e]; s = srcArr[e]; } else { d = s = e - E; }
        csr[offs[d] + rank[e]] = s;     // no atomics: rank captured during count
        return;
    }
    constexpr int NTP = 36;
    int t = threadIdx.x, nb = blockIdx.x * 32;
    if (flag[0]) {
        const float4* x4 = (const float4*)xraw;
        for (int idx = t; idx < 32 * 25; idx += 256) {
            int node = idx / 25, k4 = idx % 25;
            float4 v = x4[(size_t)(nb + node) * 25 + k4];
            xs[(k4 * 4 + 0) * NTP + node] = v.x;
            xs[(k4 * 4 + 1) * NTP + node] = v.y;
            xs[(k4 * 4 + 2) * NTP + node] = v.z;
            xs[(k4 * 4 + 3) * NTP + node] = v.w;
        }
    } else {
        const ushort4* xu = (const ushort4*)xraw;
        for (int idx = t; idx < 32 * 25; idx += 256) {
            int node = idx / 25, k4 = idx % 25;
            ushort4 u = xu[(size_t)(nb + node) * 25 + k4];
            xs[(k4 * 4 + 0) * NTP + node] = __uint_as_float((unsigned)u.x << 16);
            xs[(k4 * 4 + 1) * NTP + node] = __uint_as_float((unsigned)u.y << 16);
            xs[(k4 * 4 + 2) * NTP + node] = __uint_as_float((unsigned)u.z << 16);
            xs[(k4 * 4 + 3) * NTP + node] = __uint_as_float((unsigned)u.w << 16);
        }
    }
    __syncthreads();
    {
        int j = t & 31, g0 = t >> 5;
        float a0 = 0.f, a1 = 0.f, a2 = 0.f, a3 = 0.f;
        #pragma unroll 10
        for (int k = 0; k < 100; k++) {
            float w = aeW[k * 32 + j];
            const float4 xv = *(const float4*)&xs[k * NTP + g0 * 4];
            a0 += w * xv.x; a1 += w * xv.y; a2 += w * xv.z; a3 += w * xv.w;
        }
        float bj = aeb[j];
        axs[j * NTP + g0 * 4 + 0] = fmaxf(a0 + bj, 0.f);
        axs[j * NTP + g0 * 4 + 1] = fmaxf(a1 + bj, 0.f);
        axs[j * NTP + g0 * 4 + 2] = fmaxf(a2 + bj, 0.f);
        axs[j * NTP + g0 * 4 + 3] = fmaxf(a3 + bj, 0.f);
    }
    __syncthreads();
    {
        int j = t & 63, g0 = t >> 6;
        float aL0[2][4], aL1[2][4], aR0[2][4], aR1[2][4];
        #pragma unroll
        for (int g = 0; g < 2; g++)
            #pragma unroll
            for (int c = 0; c < 4; c++) { aL0[g][c]=0.f; aL1[g][c]=0.f; aR0[g][c]=0.f; aR1[g][c]=0.f; }
        #pragma unroll 4
        for (int k = 0; k < 32; k++) {
            float wl0 = Wl[k * 128 + j];
            float wl1 = Wl[k * 128 + j + 64];
            float wr0 = Wr[k * 128 + j];
            float wr1 = Wr[k * 128 + j + 64];
            #pragma unroll
            for (int g = 0; g < 2; g++) {
                const float4 xv = *(const float4*)&axs[k * NTP + (g0 + g * 4) * 4];
                aL0[g][0] += wl0 * xv.x; aL0[g][1] += wl0 * xv.y; aL0[g][2] += wl0 * xv.z; aL0[g][3] += wl0 * xv.w;
                aL1[g][0] += wl1 * xv.x; aL1[g][1] += wl1 * xv.y; aL1[g][2] += wl1 * xv.z; aL1[g][3] += wl1 * xv.w;
                aR0[g][0] += wr0 * xv.x; aR0[g][1] += wr0 * xv.y; aR0[g][2] += wr0 * xv.z; aR0[g][3] += wr0 * xv.w;
                aR1[g][0] += wr1 * xv.x; aR1[g][1] += wr1 * xv.y; aR1[g][2] += wr1 * xv.z; aR1[g][3] += wr1 * xv.w;
            }
        }
        float bl0 = bl[j], bl1 = bl[j + 64], br0 = br[j], br1 = br[j + 64];
        #pragma unroll
        for (int g = 0; g < 2; g++) {
            int n0 = nb + (g0 + g * 4) * 4;
            #pragma unroll
            for (int c = 0; c < 4; c++) {
                size_t row = (size_t)(n0 + c) * 128;
                outl[row + j]      = __float2half(aL0[g][c] + bl0);
                outl[row + j + 64] = __float2half(aL1[g][c] + bl1);
                outr[row + j]      = aR0[g][c] + br0;
                outr[row + j + 64] = aR1[g][c] + br1;
            }
        }
    }
}

// ====== per-edge math (16-lane group, 8 channels/lane) =======================
__device__ __forceinline__ void gat_proc(float4 raw, bool valid,
                                         const float* xrd, const float* av,
                                         float* acc, float& sm) {
    const __half2* h = (const __half2*)&raw;
    float v[8];
    float2 f;
    f = __half22float2(h[0]); v[0] = f.x; v[1] = f.y;
    f = __half22float2(h[1]); v[2] = f.x; v[3] = f.y;
    f = __half22float2(h[2]); v[4] = f.x; v[5] = f.y;
    f = __half22float2(h[3]); v[6] = f.x; v[7] = f.y;
    float p = 0.f;
    #pragma unroll
    for (int c = 0; c < 8; c++) {
        float u = v[c] + xrd[c];
        u = (u > 0.f) ? u : NEG_SLOPE * u;
        p += u * av[c];
    }
    p += __shfl_xor(p, 1);
    p += __shfl_xor(p, 2);
    p += __shfl_xor(p, 4);
    p += __shfl_xor(p, 8);
    float w = __expf(fminf(p, 80.f));
    if (!valid) w = 0.f;
    sm += w;
    #pragma unroll
    for (int c = 0; c < 8; c++) acc[c] += w * v[c];
}

// serial fallback for deg > 64 (practically never taken on this input)
__device__ void gat_one_serial(const __half* __restrict__ xl,
                               const int* __restrict__ csr, int i0, int i1,
                               const float* xrd, const float* av,
                               float* acc, float& sm, int lane, int grp, int sub) {
    for (int base = i0; base < i1; base += 64) {
        int cnt = min(i1 - base, 64);
        int myv = (lane < cnt) ? csr[base + lane] : 0;
        int nbq = (cnt + 15) >> 4;
        for (int q = 0; q < nbq; q++) {
            int e0 = q * 16 + grp;
            int s0 = __shfl(myv, e0 & 63);
            int s1 = __shfl(myv, (e0 + 4) & 63);
            int s2 = __shfl(myv, (e0 + 8) & 63);
            int s3 = __shfl(myv, (e0 + 12) & 63);
            float4 r0 = *(const float4*)(xl + (size_t)s0 * 128 + sub * 8);
            float4 r1 = *(const float4*)(xl + (size_t)s1 * 128 + sub * 8);
            float4 r2 = *(const float4*)(xl + (size_t)s2 * 128 + sub * 8);
            float4 r3 = *(const float4*)(xl + (size_t)s3 * 128 + sub * 8);
            gat_proc(r0, e0 < cnt, xrd, av, acc, sm);
            gat_proc(r1, e0 + 4 < cnt, xrd, av, acc, sm);
            gat_proc(r2, e0 + 8 < cnt, xrd, av, acc, sm);
            gat_proc(r3, e0 + 12 < cnt, xrd, av, acc, sm);
        }
    }
}

// ====== GAT H=4 gather of a 16-dst tile into LDS, dst-pair interleaved =======
// xs layout: xs[c * 20 + node], c in [0,128), node in [0,16). 10.24 KB.
__device__ __forceinline__ void gat16_to_lds(float* xs,
                                             const __half* __restrict__ xl,
                                             const float* __restrict__ xr,
                                             const float* __restrict__ att,
                                             const int* __restrict__ offs,
                                             const int* __restrict__ csr,
                                             const float* __restrict__ bias,
                                             int nb, int N) {
    int t = threadIdx.x;
    int wave = t >> 6, lane = t & 63;
    int grp = lane >> 4, sub = lane & 15;     // 4 edge-groups x 16 lanes
    float av[8];
    {
        const float4* t4 = (const float4*)(att + sub * 8);
        float4 c = t4[0], e = t4[1];
        av[0]=c.x; av[1]=c.y; av[2]=c.z; av[3]=c.w;
        av[4]=e.x; av[5]=e.y; av[6]=e.z; av[7]=e.w;
    }
    for (int it = 0; it < 4; it += 2) {
        int d0 = nb + wave * 4 + it;
        int d1 = d0 + 1;
        bool ok0 = d0 < N, ok1 = d1 < N;
        int i00 = ok0 ? offs[d0] : 0, i01 = ok0 ? offs[d0 + 1] : 0;
        int i10 = ok1 ? offs[d1] : 0, i11 = ok1 ? offs[d1 + 1] : 0;
        int cnt0 = i01 - i00, cnt1 = i11 - i10;

        float xrd0[8], xrd1[8], acc0[8], acc1[8];
        float sm0 = 0.f, sm1 = 0.f;
        #pragma unroll
        for (int c = 0; c < 8; c++) { acc0[c] = 0.f; acc1[c] = 0.f; }
        if (ok0) {
            const float4* p4 = (const float4*)(xr + (size_t)d0 * 128 + sub * 8);
            float4 a = p4[0], b = p4[1];
            xrd0[0]=a.x; xrd0[1]=a.y; xrd0[2]=a.z; xrd0[3]=a.w;
            xrd0[4]=b.x; xrd0[5]=b.y; xrd0[6]=b.z; xrd0[7]=b.w;
        }
        if (ok1) {
            const float4* p4 = (const float4*)(xr + (size_t)d1 * 128 + sub * 8);
            float4 a = p4[0], b = p4[1];
            xrd1[0]=a.x; xrd1[1]=a.y; xrd1[2]=a.z; xrd1[3]=a.w;
            xrd1[4]=b.x; xrd1[5]=b.y; xrd1[6]=b.z; xrd1[7]=b.w;
        }

        if (cnt0 <= 64 && cnt1 <= 64) {
            // fast path: both adjacency chunks register-resident, interleaved
            int myv0 = (lane < cnt0) ? csr[i00 + lane] : 0;
            int myv1 = (lane < cnt1) ? csr[i10 + lane] : 0;
            int nb0 = (cnt0 + 15) >> 4, nb1 = (cnt1 + 15) >> 4;
            int nbm = max(nb0, nb1);
            for (int q = 0; q < nbm; q++) {
                int e0 = q * 16 + grp;
                float4 r00, r01, r02, r03, r10, r11, r12, r13;
                if (q < nb0) {
                    int s0 = __shfl(myv0, e0 & 63);
                    int s1 = __shfl(myv0, (e0 + 4) & 63);
                    int s2 = __shfl(myv0, (e0 + 8) & 63);
                    int s3 = __shfl(myv0, (e0 + 12) & 63);
                    r00 = *(const float4*)(xl + (size_t)s0 * 128 + sub * 8);
                    r01 = *(const float4*)(xl + (size_t)s1 * 128 + sub * 8);
                    r02 = *(const float4*)(xl + (size_t)s2 * 128 + sub * 8);
                    r03 = *(const float4*)(xl + (size_t)s3 * 128 + sub * 8);
                }
                if (q < nb1) {
                    int s0 = __shfl(myv1, e0 & 63);
                    int s1 = __shfl(myv1, (e0 + 4) & 63);
                    int s2 = __shfl(myv1, (e0 + 8) & 63);
                    int s3 = __shfl(myv1, (e0 + 12) & 63);
                    r10 = *(const float4*)(xl + (size_t)s0 * 128 + sub * 8);
                    r11 = *(const float4*)(xl + (size_t)s1 * 128 + sub * 8);
                    r12 = *(const float4*)(xl + (size_t)s2 * 128 + sub * 8);
                    r13 = *(const float4*)(xl + (size_t)s3 * 128 + sub * 8);
                }
                if (q < nb0) {
                    gat_proc(r00, e0 < cnt0, xrd0, av, acc0, sm0);
                    gat_proc(r01, e0 + 4 < cnt0, xrd0, av, acc0, sm0);
                    gat_proc(r02, e0 + 8 < cnt0, xrd0, av, acc0, sm0);
                    gat_proc(r03, e0 + 12 < cnt0, xrd0, av, acc0, sm0);
                }
                if (q < nb1) {
                    gat_proc(r10, e0 < cnt1, xrd1, av, acc1, sm1);
                    gat_proc(r11, e0 + 4 < cnt1, xrd1, av, acc1, sm1);
                    gat_proc(r12, e0 + 8 < cnt1, xrd1, av, acc1, sm1);
                    gat_proc(r13, e0 + 12 < cnt1, xrd1, av, acc1, sm1);
                }
            }
        } else {
            if (ok0) gat_one_serial(xl, csr, i00, i01, xrd0, av, acc0, sm0, lane, grp, sub);
            if (ok1) gat_one_serial(xl, csr, i10, i11, xrd1, av, acc1, sm1, lane, grp, sub);
        }

        // full butterfly merge: all 4 groups end with the sums
        sm0 += __shfl_xor(sm0, 16); sm0 += __shfl_xor(sm0, 32);
        sm1 += __shfl_xor(sm1, 16); sm1 += __shfl_xor(sm1, 32);
        #pragma unroll
        for (int c = 0; c < 8; c++) {
            acc0[c] += __shfl_xor(acc0[c], 16); acc0[c] += __shfl_xor(acc0[c], 32);
            acc1[c] += __shfl_xor(acc1[c], 16); acc1[c] += __shfl_xor(acc1[c], 32);
        }
        // write: all 64 lanes, 2 channels each (grp selects the c-pair)
        int c2 = grp * 2;
        int ch0 = sub * 8 + c2, ch1 = ch0 + 1;
        if (ok0) {
            float inv = 1.f / (sm0 + 1e-16f);
            int node = d0 - nb;
            xs[ch0 * 20 + node] = fmaxf(acc0[c2] * inv + bias[ch0], 0.f);
            xs[ch1 * 20 + node] = fmaxf(acc0[c2 + 1] * inv + bias[ch1], 0.f);
        }
        if (ok1) {
            float inv = 1.f / (sm1 + 1e-16f);
            int node = d1 - nb;
            xs[ch0 * 20 + node] = fmaxf(acc1[c2] * inv + bias[ch0], 0.f);
            xs[ch1 * 20 + node] = fmaxf(acc1[c2 + 1] * inv + bias[ch1], 0.f);
        }
    }
}

// ====== fused: conv1 gather (16-dst tile) -> conv2 dual linear ===============
__launch_bounds__(256)
__global__ void k_gatlin(const __half* __restrict__ xl, const float* __restrict__ xr,
                         const float* __restrict__ att,
                         const int* __restrict__ offs, const int* __restrict__ csr,
                         const float* __restrict__ bias,
                         const float* __restrict__ Wl, const float* __restrict__ bl,
                         const float* __restrict__ Wr, const float* __restrict__ br,
                         __half* __restrict__ outl, float* __restrict__ outr, int N) {
    __shared__ float xs[128 * 20];
    int nb = blockIdx.x * 16;
    gat16_to_lds(xs, xl, xr, att, offs, csr, bias, nb, N);
    __syncthreads();

    int t = threadIdx.x;
    int j = t & 63, g0 = t >> 6;
    float aL0[4], aL1[4], aR0[4], aR1[4];
    #pragma unroll
    for (int c = 0; c < 4; c++) { aL0[c]=0.f; aL1[c]=0.f; aR0[c]=0.f; aR1[c]=0.f; }

    #pragma unroll 4
    for (int k = 0; k < 128; k++) {
        float wl0 = Wl[(size_t)k * 128 + j];
        float wl1 = Wl[(size_t)k * 128 + j + 64];
        float wr0 = Wr[(size_t)k * 128 + j];
        float wr1 = Wr[(size_t)k * 128 + j + 64];
        const float4 xv = *(const float4*)&xs[k * 20 + g0 * 4];
        aL0[0] += wl0 * xv.x; aL0[1] += wl0 * xv.y; aL0[2] += wl0 * xv.z; aL0[3] += wl0 * xv.w;
        aL1[0] += wl1 * xv.x; aL1[1] += wl1 * xv.y; aL1[2] += wl1 * xv.z; aL1[3] += wl1 * xv.w;
        aR0[0] += wr0 * xv.x; aR0[1] += wr0 * xv.y; aR0[2] += wr0 * xv.z; aR0[3] += wr0 * xv.w;
        aR1[0] += wr1 * xv.x; aR1[1] += wr1 * xv.y; aR1[2] += wr1 * xv.z; aR1[3] += wr1 * xv.w;
    }

    float bl0 = bl[j], bl1 = bl[j + 64], br0 = br[j], br1 = br[j + 64];
    #pragma unroll
    for (int c = 0; c < 4; c++) {
        int node = g0 * 4 + c;
        if (nb + node >= N) break;
        size_t row = (size_t)(nb + node) * 128;
        outl[row + j]      = __float2half(aL0[c] + bl0);
        outl[row + j + 64] = __float2half(aL1[c] + bl1);
        outr[row + j]      = aR0[c] + br0;
        outr[row + j + 64] = aR1[c] + br1;
    }
}

// ====== fused: conv2 gather (16-dst tile) -> global dual linear (FOUT=32) ====
__launch_bounds__(256)
__global__ void k_gatling(const __half* __restrict__ xl, const float* __restrict__ xr,
                          const float* __restrict__ att,
                          const int* __restrict__ offs, const int* __restrict__ csr,
                          const float* __restrict__ bias,
                          const float* __restrict__ Wl, const float* __restrict__ bl,
                          const float* __restrict__ Wr, const float* __restrict__ br,
                          __half* __restrict__ outl, float* __restrict__ outr, int N) {
    __shared__ float xs[128 * 20];
    int nb = blockIdx.x * 16;
    gat16_to_lds(xs, xl, xr, att, offs, csr, bias, nb, N);
    __syncthreads();

    int t = threadIdx.x;
    int j = t & 31, g0 = t >> 5;
    float aL[2], aR[2];
    aL[0]=0.f; aL[1]=0.f; aR[0]=0.f; aR[1]=0.f;

    #pragma unroll 4
    for (int k = 0; k < 128; k++) {
        float wl = Wl[(size_t)k * 32 + j];
        float wr = Wr[(size_t)k * 32 + j];
        const float2 xv = *(const float2*)&xs[k * 20 + g0 * 2];
        aL[0] += wl * xv.x; aL[1] += wl * xv.y;
        aR[0] += wr * xv.x; aR[1] += wr * xv.y;
    }

    float blj = bl[j], brj = br[j];
    #pragma unroll
    for (int c = 0; c < 2; c++) {
        int node = g0 * 2 + c;
        if (nb + node >= N) break;
        size_t row = (size_t)(nb + node) * 32;
        outl[row + j] = __float2half(aL[c] + blj);
        outr[row + j] = aR[c] + brj;
    }
}

// ===== tail: global-GAT gather for the 64 FOCAL dsts only + output head =====
__launch_bounds__(64)
__global__ void k_tailf(const __half* __restrict__ xl, const float* __restrict__ xr,
                        const float* __restrict__ att,
                        const int* __restrict__ offs, const int* __restrict__ csr,
                        const float* __restrict__ gb, const int* __restrict__ focal,
                        const float* __restrict__ clf, const float* __restrict__ clW,
                        const float* __restrict__ clb, const float* __restrict__ fcW,
                        const float* __restrict__ fcb, void* __restrict__ out,
                        const int* __restrict__ flag) {
    __shared__ float comb[64];
    __shared__ float ssb[2];
    int b = blockIdx.x;
    int t = threadIdx.x;                  // 64
    int d = focal[b];
    int grp = t >> 3, sub = t & 7;        // 8 edge-groups x 8 lanes (4 ch each)
    int i0 = offs[d], i1 = offs[d + 1];

    float xrd[4], av[4], acc[4];
    {
        float4 a = *(const float4*)(xr + (size_t)d * 32 + sub * 4);
        xrd[0]=a.x; xrd[1]=a.y; xrd[2]=a.z; xrd[3]=a.w;
        float4 c = *(const float4*)(att + sub * 4);
        av[0]=c.x; av[1]=c.y; av[2]=c.z; av[3]=c.w;
    }
    #pragma unroll
    for (int c = 0; c < 4; c++) acc[c] = 0.f;
    float sm = 0.f;

    for (int i = i0 + grp; i < i1; i += 8) {
        float2 raw = *(const float2*)(xl + (size_t)csr[i] * 32 + sub * 4);
        const __half2* h = (const __half2*)&raw;
        float v[4];
        float2 f;
        f = __half22float2(h[0]); v[0] = f.x; v[1] = f.y;
        f = __half22float2(h[1]); v[2] = f.x; v[3] = f.y;
        float p = 0.f;
        #pragma unroll
        for (int c = 0; c < 4; c++) {
            float u = v[c] + xrd[c];
            u = (u > 0.f) ? u : NEG_SLOPE * u;
            p += u * av[c];
        }
        p += __shfl_xor(p, 1);
        p += __shfl_xor(p, 2);
        p += __shfl_xor(p, 4);
        float w = __expf(fminf(p, 80.f));
        sm += w;
        #pragma unroll
        for (int c = 0; c < 4; c++) acc[c] += w * v[c];
    }
    // merge 8 edge-groups
    sm += __shfl_xor(sm, 8); sm += __shfl_xor(sm, 16); sm += __shfl_xor(sm, 32);
    #pragma unroll
    for (int c = 0; c < 4; c++) {
        acc[c] += __shfl_xor(acc[c], 8);
        acc[c] += __shfl_xor(acc[c], 16);
        acc[c] += __shfl_xor(acc[c], 32);
    }
    if (grp == 0) {
        float inv = 1.f / (sm + 1e-16f);
        #pragma unroll
        for (int c = 0; c < 4; c++)
            comb[sub * 4 + c] = fmaxf(acc[c] * inv + gb[sub * 4 + c], 0.f);
    }
    if (t < 2) {
        float s = 0.f;
        for (int l = 0; l < 50; l++) s += clf[(size_t)b * 100 + l * 2 + t];
        ssb[t] = s / 50.f;
    }
    __syncthreads();
    if (t < 32) comb[32 + t] = ssb[0] * clW[t] + ssb[1] * clW[32 + t] + clb[t];
    __syncthreads();
    if (t < 60) {
        float a2 = fcb[t];
        #pragma unroll 16
        for (int k = 0; k < 64; k++) a2 += comb[k] * fcW[k * 60 + t];
        if (flag[0]) ((float*)out)[b * 60 + t] = a2;
        else ((bf16*)out)[b * 60 + t] = __float2bfloat16(a2);
    }
}

extern "C" void kernel_launch(void* const* d_in, const int* in_sizes, int n_in,
                              void* d_out, int out_size, void* d_ws, size_t ws_size,
                              hipStream_t stream) {
    const int* edge  = (const int*)d_in[1];
    const int* focal = (const int*)d_in[5];

    const int N = in_sizes[0] / 100;   // 20000
    const int E = in_sizes[1] / 2;     // 320000
    const int B = in_sizes[5];         // 64
    const int EA = E + N;
    const int* srcArr = edge;
    const int* dstArr = edge + E;

    // ---- conversion table: weights + centerlines -> fp32 in ws (x stays raw)
    const int idxs[NSEG] = {7,8,9,10,11,12,13,14,15,16,17,18,19,20,
                            35,36,37,38,39,40,41,42,43,44, 6};
    float* base = (float*)d_ws;
    int* flag = (int*)base;            // base[0..15] reserved
    float* wf = base + 16;
    Tab tab;
    int off[NSEG];
    int o = 0;
    for (int i = 0; i < NSEG; i++) {
        tab.s[i].src = d_in[idxs[i]];
        tab.s[i].n   = in_sizes[idxs[i]];
        tab.s[i].off = o;
        off[i] = o;
        o += in_sizes[idxs[i]];
    }
    const float* aeW  = wf + off[0],  *aeb  = wf + off[1];
    const float* a1Wl = wf + off[2],  *a1bl = wf + off[3];
    const float* a1Wr = wf + off[4],  *a1br = wf + off[5];
    const float* a1att= wf + off[6],  *a1b  = wf + off[7];
    const float* a2Wl = wf + off[8],  *a2bl = wf + off[9];
    const float* a2Wr = wf + off[10], *a2br = wf + off[11];
    const float* a2att= wf + off[12], *a2b  = wf + off[13];
    const float* clW  = wf + off[14], *clb  = wf + off[15];
    const float* gWl  = wf + off[16], *gbl  = wf + off[17];
    const float* gWr  = wf + off[18], *gbr  = wf + off[19];
    const float* gatt = wf + off[20], *gb   = wf + off[21];
    const float* fcW  = wf + off[22], *fcb  = wf + off[23];
    const float* clf  = wf + off[24];

    // ---- remaining workspace (keep 16B alignment) ----
    float* p = wf + o + ((4 - (o & 3)) & 3);
    size_t N128 = (size_t)N * 128;
    __half* hxl1 = (__half*)p;      p += (size_t)N * 64;    // conv1 xl fp16 [N,128]; later global xl [N,32]
    float* fB1  = p;                p += N128;              // conv1 xr fp32; later global xrg [N,32]
    __half* hxl2 = (__half*)p;      p += (size_t)N * 64;    // conv2 xl fp16 [N,128]
    float* fB2  = p;                p += N128;              // conv2 xr fp32
    int* deg    = (int*)p;          // [N]
    int* st     = deg + N;          // [32] scan lookback state
    int* offs   = st + 32;          // N+1
    int* rank   = offs + N + 1;     // EA
    int* csr    = rank + EA;        // EA (src node ids)

    const int NB = (N + 1023) / 1024;          // scan tiles (20)
    const int EB = N / 32;                     // embedlin blocks (625)
    const int FBLK = (EA + 255) / 256;         // fill blocks
    const int GT = (N + 15) / 16;              // fused gather+linear tiles (1250)

    // ---- detect + zero deg/st ----
    k_detect_zero<<<64, 256, 0, stream>>>((const unsigned short*)d_in[0], flag, deg, N + 32);
    // ---- convert weights + degree count with rank capture ----
    k_convert<<<256, 256, 0, stream>>>(tab, wf, flag, dstArr, E, N, deg, rank);
    // ---- single-kernel lookback scan ----
    k_scanf<<<NB, 1024, 0, stream>>>(deg, offs, N, st, NB);
    // ---- CSR fill (rank trick) + fused embed+conv1-linear -> hxl1/fB1 ----
    k_fill_embedlin<<<EB + FBLK, 256, 0, stream>>>(srcArr, dstArr, E, N, offs, rank, csr,
                                                   d_in[0], flag, aeW, aeb,
                                                   a1Wl, a1bl, a1Wr, a1br, hxl1, fB1, EB);
    // ---- conv1 gather + conv2 linear (fC stays in LDS) -> hxl2/fB2 ----
    k_gatlin<<<GT, 256, 0, stream>>>(hxl1, fB1, a1att, offs, csr, a1b,
                                     a2Wl, a2bl, a2Wr, a2br, hxl2, fB2, N);
    // ---- conv2 gather + global linear -> hxl1([N,32]) / fB1([N,32]) ----
    k_gatling<<<GT, 256, 0, stream>>>(hxl2, fB2, a2att, offs, csr, a2b,
                                      gWl, gbl, gWr, gbr, hxl1, fB1, N);
    // ---- tail: global gather for the 64 focal dsts + head ----
    k_tailf<<<B, 64, 0, stream>>>(hxl1, fB1, gatt, offs, csr, gb, focal,
                                  clf, clW, clb, fcW, fcb, d_out, flag);
}

// Round 14
// 295.819 us; speedup vs baseline: 6.1793x; 1.0178x over previous
//
#include <hip/hip_runtime.h>
#include <hip/hip_bf16.h>
#include <hip/hip_fp16.h>
#include <math.h>

typedef __hip_bfloat16 bf16;
#define NEG_SLOPE 0.2f
#define SFLAG (1 << 30)

typedef _Float16 f16x8 __attribute__((ext_vector_type(8)));
typedef float f32x4 __attribute__((ext_vector_type(4)));

// ====== dtype detect (block 0) + zero deg/scan-state =========================
__global__ void k_detect_zero(const unsigned short* __restrict__ x, int* __restrict__ flag,
                              int* __restrict__ zbase, int n) {
    for (int i = blockIdx.x * blockDim.x + threadIdx.x; i < n; i += gridDim.x * blockDim.x)
        zbase[i] = 0;
    if (blockIdx.x == 0) {
        __shared__ int cnt;
        if (threadIdx.x == 0) cnt = 0;
        __syncthreads();
        int local = 0;
        for (int i = threadIdx.x; i < 2048; i += blockDim.x) {
            unsigned short w = x[2 * i];
            int e = (w >> 7) & 0xFF;
            if (e >= 0x90) local++;
        }
        atomicAdd(&cnt, local);
        __syncthreads();
        if (threadIdx.x == 0) flag[0] = (cnt > 100) ? 1 : 0;  // 1 => inputs are f32
    }
}

#define NSEG 25
struct Seg { const void* src; int n; int off; };
struct Tab { Seg s[NSEG]; };

__device__ __forceinline__ float ldconv(const void* src, int i, int f32mode) {
    return f32mode ? ((const float*)src)[i]
                   : __bfloat162float(((const bf16*)src)[i]);
}

// ====== convert weights fp32 + transposed f16 weights + degree/rank ==========
__global__ void k_convert(Tab tab, float* __restrict__ dst, const int* __restrict__ flag,
                          const int* __restrict__ dstArr, int E, int N,
                          int* __restrict__ deg, int* __restrict__ rank,
                          const void* a2WlS, const void* a2WrS,
                          const void* gWlS, const void* gWrS,
                          __half* __restrict__ a2Wlt, __half* __restrict__ a2Wrt,
                          __half* __restrict__ gWlt, __half* __restrict__ gWrt) {
    int f32mode = flag[0];
    int gid = blockIdx.x * blockDim.x + threadIdx.x;
    int gsz = gridDim.x * blockDim.x;
    for (int s = 0; s < NSEG; s++) {
        Seg sg = tab.s[s];
        for (int i = gid; i < sg.n; i += gsz) {
            dst[sg.off + i] = ldconv(sg.src, i, f32mode);
        }
    }
    // transposed f16 weights: Wt[j][k] = W[k][j]
    for (int i = gid; i < 128 * 128; i += gsz) {
        int k = i >> 7, j = i & 127;
        a2Wlt[(size_t)j * 128 + k] = __float2half(ldconv(a2WlS, i, f32mode));
        a2Wrt[(size_t)j * 128 + k] = __float2half(ldconv(a2WrS, i, f32mode));
    }
    for (int i = gid; i < 128 * 32; i += gsz) {
        int k = i >> 5, j = i & 31;
        gWlt[(size_t)j * 128 + k] = __float2half(ldconv(gWlS, i, f32mode));
        gWrt[(size_t)j * 128 + k] = __float2half(ldconv(gWrS, i, f32mode));
    }
    int EA = E + N;
    for (int e = gid; e < EA; e += gsz) {
        int d = (e < E) ? dstArr[e] : (e - E);
        rank[e] = atomicAdd(&deg[d], 1);
    }
}

// ====== single-kernel chained-lookback exclusive scan ========================
__launch_bounds__(1024)
__global__ void k_scanf(const int* __restrict__ deg, int* __restrict__ offs,
                        int n, int* __restrict__ st, int nb) {
    __shared__ int ws[16];
    __shared__ int stot, sprev;
    int tile = blockIdx.x;
    int i = tile * 1024 + threadIdx.x;
    int lane = threadIdx.x & 63, wid = threadIdx.x >> 6;
    int v = (i < n) ? deg[i] : 0;
    int x = v;
    #pragma unroll
    for (int o = 1; o < 64; o <<= 1) {
        int y = __shfl_up(x, o);
        if (lane >= o) x += y;
    }
    if (lane == 63) ws[wid] = x;
    __syncthreads();
    if (wid == 0) {
        int w = (lane < 16) ? ws[lane] : 0;
        int s = w;
        #pragma unroll
        for (int o = 1; o < 16; o <<= 1) {
            int y = __shfl_up(s, o);
            if (lane >= o) s += y;
        }
        if (lane < 16) ws[lane] = s - w;
        if (lane == 15) stot = s;
    }
    __syncthreads();
    int local = ws[wid] + x - v;     // block-local exclusive
    if (threadIdx.x == 0) {
        int prev = 0;
        if (tile > 0) {
            int vv;
            while ((((vv = __hip_atomic_load(&st[tile - 1], __ATOMIC_ACQUIRE,
                                             __HIP_MEMORY_SCOPE_AGENT))) & SFLAG) == 0) {}
            prev = vv & ~SFLAG;
        }
        __hip_atomic_store(&st[tile], (prev + stot) | SFLAG, __ATOMIC_RELEASE,
                           __HIP_MEMORY_SCOPE_AGENT);
        sprev = prev;
        if (tile == nb - 1) offs[n] = prev + stot;
    }
    __syncthreads();
    if (i < n) offs[i] = sprev + local;
}

// ====== fused: CSR fill via rank (blocks >= EB) + embed+conv1-linear =========
__launch_bounds__(256)
__global__ void k_fill_embedlin(const int* __restrict__ srcArr, const int* __restrict__ dstArr,
                                int E, int N, const int* __restrict__ offs,
                                const int* __restrict__ rank, int* __restrict__ csr,
                                const void* __restrict__ xraw, const int* __restrict__ flag,
                                const float* __restrict__ aeW, const float* __restrict__ aeb,
                                const float* __restrict__ Wl, const float* __restrict__ bl,
                                const float* __restrict__ Wr, const float* __restrict__ br,
                                __half* __restrict__ outl, float* __restrict__ outr,
                                int EB) {
    __shared__ float xs[100 * 36];
    __shared__ float axs[32 * 36];
    if (blockIdx.x >= EB) {
        int e = (blockIdx.x - EB) * 256 + threadIdx.x;
        int EA = E + N;
        if (e >= EA) return;
        int d, s;
        if (e < E) { d = dstArr[e]; s = srcArr[e]; } else { d = s = e - E; }
        csr[offs[d] + rank[e]] = s;     // no atomics: rank captured during count
        return;
    }
    constexpr int NTP = 36;
    int t = threadIdx.x, nb = blockIdx.x * 32;
    if (flag[0]) {
        const float4* x4 = (const float4*)xraw;
        for (int idx = t; idx < 32 * 25; idx += 256) {
            int node = idx / 25, k4 = idx % 25;
            float4 v = x4[(size_t)(nb + node) * 25 + k4];
            xs[(k4 * 4 + 0) * NTP + node] = v.x;
            xs[(k4 * 4 + 1) * NTP + node] = v.y;
            xs[(k4 * 4 + 2) * NTP + node] = v.z;
            xs[(k4 * 4 + 3) * NTP + node] = v.w;
        }
    } else {
        const ushort4* xu = (const ushort4*)xraw;
        for (int idx = t; idx < 32 * 25; idx += 256) {
            int node = idx / 25, k4 = idx % 25;
            ushort4 u = xu[(size_t)(nb + node) * 25 + k4];
            xs[(k4 * 4 + 0) * NTP + node] = __uint_as_float((unsigned)u.x << 16);
            xs[(k4 * 4 + 1) * NTP + node] = __uint_as_float((unsigned)u.y << 16);
            xs[(k4 * 4 + 2) * NTP + node] = __uint_as_float((unsigned)u.z << 16);
            xs[(k4 * 4 + 3) * NTP + node] = __uint_as_float((unsigned)u.w << 16);
        }
    }
    __syncthreads();
    {
        int j = t & 31, g0 = t >> 5;
        float a0 = 0.f, a1 = 0.f, a2 = 0.f, a3 = 0.f;
        #pragma unroll 10
        for (int k = 0; k < 100; k++) {
            float w = aeW[k * 32 + j];
            const float4 xv = *(const float4*)&xs[k * NTP + g0 * 4];
            a0 += w * xv.x; a1 += w * xv.y; a2 += w * xv.z; a3 += w * xv.w;
        }
        float bj = aeb[j];
        axs[j * NTP + g0 * 4 + 0] = fmaxf(a0 + bj, 0.f);
        axs[j * NTP + g0 * 4 + 1] = fmaxf(a1 + bj, 0.f);
        axs[j * NTP + g0 * 4 + 2] = fmaxf(a2 + bj, 0.f);
        axs[j * NTP + g0 * 4 + 3] = fmaxf(a3 + bj, 0.f);
    }
    __syncthreads();
    {
        int j = t & 63, g0 = t >> 6;
        float aL0[2][4], aL1[2][4], aR0[2][4], aR1[2][4];
        #pragma unroll
        for (int g = 0; g < 2; g++)
            #pragma unroll
            for (int c = 0; c < 4; c++) { aL0[g][c]=0.f; aL1[g][c]=0.f; aR0[g][c]=0.f; aR1[g][c]=0.f; }
        #pragma unroll 4
        for (int k = 0; k < 32; k++) {
            float wl0 = Wl[k * 128 + j];
            float wl1 = Wl[k * 128 + j + 64];
            float wr0 = Wr[k * 128 + j];
            float wr1 = Wr[k * 128 + j + 64];
            #pragma unroll
            for (int g = 0; g < 2; g++) {
                const float4 xv = *(const float4*)&axs[k * NTP + (g0 + g * 4) * 4];
                aL0[g][0] += wl0 * xv.x; aL0[g][1] += wl0 * xv.y; aL0[g][2] += wl0 * xv.z; aL0[g][3] += wl0 * xv.w;
                aL1[g][0] += wl1 * xv.x; aL1[g][1] += wl1 * xv.y; aL1[g][2] += wl1 * xv.z; aL1[g][3] += wl1 * xv.w;
                aR0[g][0] += wr0 * xv.x; aR0[g][1] += wr0 * xv.y; aR0[g][2] += wr0 * xv.z; aR0[g][3] += wr0 * xv.w;
                aR1[g][0] += wr1 * xv.x; aR1[g][1] += wr1 * xv.y; aR1[g][2] += wr1 * xv.z; aR1[g][3] += wr1 * xv.w;
            }
        }
        float bl0 = bl[j], bl1 = bl[j + 64], br0 = br[j], br1 = br[j + 64];
        #pragma unroll
        for (int g = 0; g < 2; g++) {
            int n0 = nb + (g0 + g * 4) * 4;
            #pragma unroll
            for (int c = 0; c < 4; c++) {
                size_t row = (size_t)(n0 + c) * 128;
                outl[row + j]      = __float2half(aL0[g][c] + bl0);
                outl[row + j + 64] = __float2half(aL1[g][c] + bl1);
                outr[row + j]      = aR0[g][c] + br0;
                outr[row + j + 64] = aR1[g][c] + br1;
            }
        }
    }
}

// ====== per-edge math (16-lane group, 8 channels/lane) =======================
__device__ __forceinline__ void gat_proc(float4 raw, bool valid,
                                         const float* xrd, const float* av,
                                         float* acc, float& sm) {
    const __half2* h = (const __half2*)&raw;
    float v[8];
    float2 f;
    f = __half22float2(h[0]); v[0] = f.x; v[1] = f.y;
    f = __half22float2(h[1]); v[2] = f.x; v[3] = f.y;
    f = __half22float2(h[2]); v[4] = f.x; v[5] = f.y;
    f = __half22float2(h[3]); v[6] = f.x; v[7] = f.y;
    float p = 0.f;
    #pragma unroll
    for (int c = 0; c < 8; c++) {
        float u = v[c] + xrd[c];
        u = (u > 0.f) ? u : NEG_SLOPE * u;
        p += u * av[c];
    }
    p += __shfl_xor(p, 1);
    p += __shfl_xor(p, 2);
    p += __shfl_xor(p, 4);
    p += __shfl_xor(p, 8);
    float w = __expf(fminf(p, 80.f));
    if (!valid) w = 0.f;
    sm += w;
    #pragma unroll
    for (int c = 0; c < 8; c++) acc[c] += w * v[c];
}

// serial fallback for deg > 64 (practically never taken on this input)
__device__ void gat_one_serial(const __half* __restrict__ xl,
                               const int* __restrict__ csr, int i0, int i1,
                               const float* xrd, const float* av,
                               float* acc, float& sm, int lane, int grp, int sub) {
    for (int base = i0; base < i1; base += 64) {
        int cnt = min(i1 - base, 64);
        int myv = (lane < cnt) ? csr[base + lane] : 0;
        int nbq = (cnt + 15) >> 4;
        for (int q = 0; q < nbq; q++) {
            int e0 = q * 16 + grp;
            int s0 = __shfl(myv, e0 & 63);
            int s1 = __shfl(myv, (e0 + 4) & 63);
            int s2 = __shfl(myv, (e0 + 8) & 63);
            int s3 = __shfl(myv, (e0 + 12) & 63);
            float4 r0 = *(const float4*)(xl + (size_t)s0 * 128 + sub * 8);
            float4 r1 = *(const float4*)(xl + (size_t)s1 * 128 + sub * 8);
            float4 r2 = *(const float4*)(xl + (size_t)s2 * 128 + sub * 8);
            float4 r3 = *(const float4*)(xl + (size_t)s3 * 128 + sub * 8);
            gat_proc(r0, e0 < cnt, xrd, av, acc, sm);
            gat_proc(r1, e0 + 4 < cnt, xrd, av, acc, sm);
            gat_proc(r2, e0 + 8 < cnt, xrd, av, acc, sm);
            gat_proc(r3, e0 + 12 < cnt, xrd, av, acc, sm);
        }
    }
}

// ====== GAT H=4 gather of a 16-dst tile into LDS (fp16, node-major) ==========
// xsh layout: xsh[node * 136 + ch], node in [0,16), ch in [0,128). 4.35 KB.
__device__ __forceinline__ void gat16_to_lds(__half* xsh,
                                             const __half* __restrict__ xl,
                                             const float* __restrict__ xr,
                                             const float* __restrict__ att,
                                             const int* __restrict__ offs,
                                             const int* __restrict__ csr,
                                             const float* __restrict__ bias,
                                             int nb, int N) {
    int t = threadIdx.x;
    int wave = t >> 6, lane = t & 63;
    int grp = lane >> 4, sub = lane & 15;     // 4 edge-groups x 16 lanes
    float av[8];
    {
        const float4* t4 = (const float4*)(att + sub * 8);
        float4 c = t4[0], e = t4[1];
        av[0]=c.x; av[1]=c.y; av[2]=c.z; av[3]=c.w;
        av[4]=e.x; av[5]=e.y; av[6]=e.z; av[7]=e.w;
    }
    for (int it = 0; it < 4; it += 2) {
        int d0 = nb + wave * 4 + it;
        int d1 = d0 + 1;
        bool ok0 = d0 < N, ok1 = d1 < N;
        int i00 = ok0 ? offs[d0] : 0, i01 = ok0 ? offs[d0 + 1] : 0;
        int i10 = ok1 ? offs[d1] : 0, i11 = ok1 ? offs[d1 + 1] : 0;
        int cnt0 = i01 - i00, cnt1 = i11 - i10;

        float xrd0[8], xrd1[8], acc0[8], acc1[8];
        float sm0 = 0.f, sm1 = 0.f;
        #pragma unroll
        for (int c = 0; c < 8; c++) { acc0[c] = 0.f; acc1[c] = 0.f; }
        if (ok0) {
            const float4* p4 = (const float4*)(xr + (size_t)d0 * 128 + sub * 8);
            float4 a = p4[0], b = p4[1];
            xrd0[0]=a.x; xrd0[1]=a.y; xrd0[2]=a.z; xrd0[3]=a.w;
            xrd0[4]=b.x; xrd0[5]=b.y; xrd0[6]=b.z; xrd0[7]=b.w;
        }
        if (ok1) {
            const float4* p4 = (const float4*)(xr + (size_t)d1 * 128 + sub * 8);
            float4 a = p4[0], b = p4[1];
            xrd1[0]=a.x; xrd1[1]=a.y; xrd1[2]=a.z; xrd1[3]=a.w;
            xrd1[4]=b.x; xrd1[5]=b.y; xrd1[6]=b.z; xrd1[7]=b.w;
        }

        if (cnt0 <= 64 && cnt1 <= 64) {
            int myv0 = (lane < cnt0) ? csr[i00 + lane] : 0;
            int myv1 = (lane < cnt1) ? csr[i10 + lane] : 0;
            int nb0 = (cnt0 + 15) >> 4, nb1 = (cnt1 + 15) >> 4;
            int nbm = max(nb0, nb1);
            for (int q = 0; q < nbm; q++) {
                int e0 = q * 16 + grp;
                float4 r00, r01, r02, r03, r10, r11, r12, r13;
                if (q < nb0) {
                    int s0 = __shfl(myv0, e0 & 63);
                    int s1 = __shfl(myv0, (e0 + 4) & 63);
                    int s2 = __shfl(myv0, (e0 + 8) & 63);
                    int s3 = __shfl(myv0, (e0 + 12) & 63);
                    r00 = *(const float4*)(xl + (size_t)s0 * 128 + sub * 8);
                    r01 = *(const float4*)(xl + (size_t)s1 * 128 + sub * 8);
                    r02 = *(const float4*)(xl + (size_t)s2 * 128 + sub * 8);
                    r03 = *(const float4*)(xl + (size_t)s3 * 128 + sub * 8);
                }
                if (q < nb1) {
                    int s0 = __shfl(myv1, e0 & 63);
                    int s1 = __shfl(myv1, (e0 + 4) & 63);
                    int s2 = __shfl(myv1, (e0 + 8) & 63);
                    int s3 = __shfl(myv1, (e0 + 12) & 63);
                    r10 = *(const float4*)(xl + (size_t)s0 * 128 + sub * 8);
                    r11 = *(const float4*)(xl + (size_t)s1 * 128 + sub * 8);
                    r12 = *(const float4*)(xl + (size_t)s2 * 128 + sub * 8);
                    r13 = *(const float4*)(xl + (size_t)s3 * 128 + sub * 8);
                }
                if (q < nb0) {
                    gat_proc(r00, e0 < cnt0, xrd0, av, acc0, sm0);
                    gat_proc(r01, e0 + 4 < cnt0, xrd0, av, acc0, sm0);
                    gat_proc(r02, e0 + 8 < cnt0, xrd0, av, acc0, sm0);
                    gat_proc(r03, e0 + 12 < cnt0, xrd0, av, acc0, sm0);
                }
                if (q < nb1) {
                    gat_proc(r10, e0 < cnt1, xrd1, av, acc1, sm1);
                    gat_proc(r11, e0 + 4 < cnt1, xrd1, av, acc1, sm1);
                    gat_proc(r12, e0 + 8 < cnt1, xrd1, av, acc1, sm1);
                    gat_proc(r13, e0 + 12 < cnt1, xrd1, av, acc1, sm1);
                }
            }
        } else {
            if (ok0) gat_one_serial(xl, csr, i00, i01, xrd0, av, acc0, sm0, lane, grp, sub);
            if (ok1) gat_one_serial(xl, csr, i10, i11, xrd1, av, acc1, sm1, lane, grp, sub);
        }

        // full butterfly merge: all 4 groups end with the sums
        sm0 += __shfl_xor(sm0, 16); sm0 += __shfl_xor(sm0, 32);
        sm1 += __shfl_xor(sm1, 16); sm1 += __shfl_xor(sm1, 32);
        #pragma unroll
        for (int c = 0; c < 8; c++) {
            acc0[c] += __shfl_xor(acc0[c], 16); acc0[c] += __shfl_xor(acc0[c], 32);
            acc1[c] += __shfl_xor(acc1[c], 16); acc1[c] += __shfl_xor(acc1[c], 32);
        }
        // write fp16 node-major: all 64 lanes, 2 channels each
        int c2 = grp * 2;
        int ch0 = sub * 8 + c2;
        if (ok0) {
            float inv = 1.f / (sm0 + 1e-16f);
            int node = d0 - nb;
            __half2 hv;
            hv.x = __float2half(fmaxf(acc0[c2] * inv + bias[ch0], 0.f));
            hv.y = __float2half(fmaxf(acc0[c2 + 1] * inv + bias[ch0 + 1], 0.f));
            *(__half2*)&xsh[node * 136 + ch0] = hv;
        }
        if (ok1) {
            float inv = 1.f / (sm1 + 1e-16f);
            int node = d1 - nb;
            __half2 hv;
            hv.x = __float2half(fmaxf(acc1[c2] * inv + bias[ch0], 0.f));
            hv.y = __float2half(fmaxf(acc1[c2 + 1] * inv + bias[ch0 + 1], 0.f));
            *(__half2*)&xsh[node * 136 + ch0] = hv;
        }
    }
}

// ====== fused: conv1 gather (16-dst tile) -> conv2 dual linear via MFMA ======
__launch_bounds__(256)
__global__ void k_gatlin(const __half* __restrict__ xl, const float* __restrict__ xr,
                         const float* __restrict__ att,
                         const int* __restrict__ offs, const int* __restrict__ csr,
                         const float* __restrict__ bias,
                         const __half* __restrict__ Wlt, const float* __restrict__ bl,
                         const __half* __restrict__ Wrt, const float* __restrict__ br,
                         __half* __restrict__ outl, float* __restrict__ outr, int N) {
    __shared__ __align__(16) __half xsh[16 * 136];
    int nb = blockIdx.x * 16;
    gat16_to_lds(xsh, xl, xr, att, offs, csr, bias, nb, N);
    __syncthreads();

    int t = threadIdx.x;
    int lane = t & 63, wv = t >> 6;
    int quad = lane >> 4, n16 = lane & 15;
    // A fragments: A[m=lane&15][k=quad*8+i], 4 k-tiles of 32
    f16x8 a[4];
    #pragma unroll
    for (int kt = 0; kt < 4; kt++)
        a[kt] = *(const f16x8*)&xsh[n16 * 136 + kt * 32 + quad * 8];

    int j0 = wv * 32;   // this wave's 32 output columns (two 16-tiles), for L and R
    f32x4 aL0 = {0.f,0.f,0.f,0.f}, aL1 = {0.f,0.f,0.f,0.f};
    f32x4 aR0 = {0.f,0.f,0.f,0.f}, aR1 = {0.f,0.f,0.f,0.f};
    #pragma unroll
    for (int kt = 0; kt < 4; kt++) {
        int ko = kt * 32 + quad * 8;
        f16x8 b0 = *(const f16x8*)&Wlt[(size_t)(j0 + n16) * 128 + ko];
        f16x8 b1 = *(const f16x8*)&Wlt[(size_t)(j0 + 16 + n16) * 128 + ko];
        f16x8 b2 = *(const f16x8*)&Wrt[(size_t)(j0 + n16) * 128 + ko];
        f16x8 b3 = *(const f16x8*)&Wrt[(size_t)(j0 + 16 + n16) * 128 + ko];
        aL0 = __builtin_amdgcn_mfma_f32_16x16x32_f16(a[kt], b0, aL0, 0, 0, 0);
        aL1 = __builtin_amdgcn_mfma_f32_16x16x32_f16(a[kt], b1, aL1, 0, 0, 0);
        aR0 = __builtin_amdgcn_mfma_f32_16x16x32_f16(a[kt], b2, aR0, 0, 0, 0);
        aR1 = __builtin_amdgcn_mfma_f32_16x16x32_f16(a[kt], b3, aR1, 0, 0, 0);
    }
    float blj0 = bl[j0 + n16], blj1 = bl[j0 + 16 + n16];
    float brj0 = br[j0 + n16], brj1 = br[j0 + 16 + n16];
    #pragma unroll
    for (int r = 0; r < 4; r++) {
        int node = quad * 4 + r;        // D row = node
        if (nb + node >= N) continue;
        size_t row = (size_t)(nb + node) * 128;
        outl[row + j0 + n16]      = __float2half(aL0[r] + blj0);
        outl[row + j0 + 16 + n16] = __float2half(aL1[r] + blj1);
        outr[row + j0 + n16]      = aR0[r] + brj0;
        outr[row + j0 + 16 + n16] = aR1[r] + brj1;
    }
}

// ====== fused: conv2 gather (16-dst tile) -> global linear (FOUT=32) MFMA ====
__launch_bounds__(256)
__global__ void k_gatling(const __half* __restrict__ xl, const float* __restrict__ xr,
                          const float* __restrict__ att,
                          const int* __restrict__ offs, const int* __restrict__ csr,
                          const float* __restrict__ bias,
                          const __half* __restrict__ Wlt, const float* __restrict__ bl,
                          const __half* __restrict__ Wrt, const float* __restrict__ br,
                          __half* __restrict__ outl, float* __restrict__ outr, int N) {
    __shared__ __align__(16) __half xsh[16 * 136];
    int nb = blockIdx.x * 16;
    gat16_to_lds(xsh, xl, xr, att, offs, csr, bias, nb, N);
    __syncthreads();

    int t = threadIdx.x;
    int lane = t & 63, wv = t >> 6;
    int quad = lane >> 4, n16 = lane & 15;
    f16x8 a[4];
    #pragma unroll
    for (int kt = 0; kt < 4; kt++)
        a[kt] = *(const f16x8*)&xsh[n16 * 136 + kt * 32 + quad * 8];

    // wave -> one 16x16 tile: wv 0: L j0=0; 1: L j0=16; 2: R j0=0; 3: R j0=16
    const __half* Wt = (wv < 2) ? Wlt : Wrt;
    int j0 = (wv & 1) * 16;
    f32x4 accv = {0.f,0.f,0.f,0.f};
    #pragma unroll
    for (int kt = 0; kt < 4; kt++) {
        f16x8 b = *(const f16x8*)&Wt[(size_t)(j0 + n16) * 128 + kt * 32 + quad * 8];
        accv = __builtin_amdgcn_mfma_f32_16x16x32_f16(a[kt], b, accv, 0, 0, 0);
    }
    float bj = ((wv < 2) ? bl : br)[j0 + n16];
    #pragma unroll
    for (int r = 0; r < 4; r++) {
        int node = quad * 4 + r;
        if (nb + node >= N) continue;
        size_t row = (size_t)(nb + node) * 32;
        if (wv < 2) outl[row + j0 + n16] = __float2half(accv[r] + bj);
        else        outr[row + j0 + n16] = accv[r] + bj;
    }
}

// ===== tail: global-GAT gather for the 64 FOCAL dsts only + output head =====
__launch_bounds__(64)
__global__ void k_tailf(const __half* __restrict__ xl, const float* __restrict__ xr,
                        const float* __restrict__ att,
                        const int* __restrict__ offs, const int* __restrict__ csr,
                        const float* __restrict__ gb, const int* __restrict__ focal,
                        const float* __restrict__ clf, const float* __restrict__ clW,
                        const float* __restrict__ clb, const float* __restrict__ fcW,
                        const float* __restrict__ fcb, void* __restrict__ out,
                        const int* __restrict__ flag) {
    __shared__ float comb[64];
    __shared__ float ssb[2];
    int b = blockIdx.x;
    int t = threadIdx.x;                  // 64
    int d = focal[b];
    int grp = t >> 3, sub = t & 7;        // 8 edge-groups x 8 lanes (4 ch each)
    int i0 = offs[d], i1 = offs[d + 1];

    float xrd[4], av[4], acc[4];
    {
        float4 a = *(const float4*)(xr + (size_t)d * 32 + sub * 4);
        xrd[0]=a.x; xrd[1]=a.y; xrd[2]=a.z; xrd[3]=a.w;
        float4 c = *(const float4*)(att + sub * 4);
        av[0]=c.x; av[1]=c.y; av[2]=c.z; av[3]=c.w;
    }
    #pragma unroll
    for (int c = 0; c < 4; c++) acc[c] = 0.f;
    float sm = 0.f;

    for (int i = i0 + grp; i < i1; i += 8) {
        float2 raw = *(const float2*)(xl + (size_t)csr[i] * 32 + sub * 4);
        const __half2* h = (const __half2*)&raw;
        float v[4];
        float2 f;
        f = __half22float2(h[0]); v[0] = f.x; v[1] = f.y;
        f = __half22float2(h[1]); v[2] = f.x; v[3] = f.y;
        float p = 0.f;
        #pragma unroll
        for (int c = 0; c < 4; c++) {
            float u = v[c] + xrd[c];
            u = (u > 0.f) ? u : NEG_SLOPE * u;
            p += u * av[c];
        }
        p += __shfl_xor(p, 1);
        p += __shfl_xor(p, 2);
        p += __shfl_xor(p, 4);
        float w = __expf(fminf(p, 80.f));
        sm += w;
        #pragma unroll
        for (int c = 0; c < 4; c++) acc[c] += w * v[c];
    }
    // merge 8 edge-groups
    sm += __shfl_xor(sm, 8); sm += __shfl_xor(sm, 16); sm += __shfl_xor(sm, 32);
    #pragma unroll
    for (int c = 0; c < 4; c++) {
        acc[c] += __shfl_xor(acc[c], 8);
        acc[c] += __shfl_xor(acc[c], 16);
        acc[c] += __shfl_xor(acc[c], 32);
    }
    if (grp == 0) {
        float inv = 1.f / (sm + 1e-16f);
        #pragma unroll
        for (int c = 0; c < 4; c++)
            comb[sub * 4 + c] = fmaxf(acc[c] * inv + gb[sub * 4 + c], 0.f);
    }
    if (t < 2) {
        float s = 0.f;
        for (int l = 0; l < 50; l++) s += clf[(size_t)b * 100 + l * 2 + t];
        ssb[t] = s / 50.f;
    }
    __syncthreads();
    if (t < 32) comb[32 + t] = ssb[0] * clW[t] + ssb[1] * clW[32 + t] + clb[t];
    __syncthreads();
    if (t < 60) {
        float a2 = fcb[t];
        #pragma unroll 16
        for (int k = 0; k < 64; k++) a2 += comb[k] * fcW[k * 60 + t];
        if (flag[0]) ((float*)out)[b * 60 + t] = a2;
        else ((bf16*)out)[b * 60 + t] = __float2bfloat16(a2);
    }
}

extern "C" void kernel_launch(void* const* d_in, const int* in_sizes, int n_in,
                              void* d_out, int out_size, void* d_ws, size_t ws_size,
                              hipStream_t stream) {
    const int* edge  = (const int*)d_in[1];
    const int* focal = (const int*)d_in[5];

    const int N = in_sizes[0] / 100;   // 20000
    const int E = in_sizes[1] / 2;     // 320000
    const int B = in_sizes[5];         // 64
    const int EA = E + N;
    const int* srcArr = edge;
    const int* dstArr = edge + E;

    // ---- conversion table: weights + centerlines -> fp32 in ws (x stays raw)
    const int idxs[NSEG] = {7,8,9,10,11,12,13,14,15,16,17,18,19,20,
                            35,36,37,38,39,40,41,42,43,44, 6};
    float* base = (float*)d_ws;
    int* flag = (int*)base;            // base[0..15] reserved
    float* wf = base + 16;
    Tab tab;
    int off[NSEG];
    int o = 0;
    for (int i = 0; i < NSEG; i++) {
        tab.s[i].src = d_in[idxs[i]];
        tab.s[i].n   = in_sizes[idxs[i]];
        tab.s[i].off = o;
        off[i] = o;
        o += in_sizes[idxs[i]];
    }
    const float* aeW  = wf + off[0],  *aeb  = wf + off[1];
    const float* a1Wl = wf + off[2],  *a1bl = wf + off[3];
    const float* a1Wr = wf + off[4],  *a1br = wf + off[5];
    const float* a1att= wf + off[6],  *a1b  = wf + off[7];
    const float* a2bl = wf + off[9];
    const float* a2br = wf + off[11];
    const float* a2att= wf + off[12], *a2b  = wf + off[13];
    const float* clW  = wf + off[14], *clb  = wf + off[15];
    const float* gbl  = wf + off[17];
    const float* gbr  = wf + off[19];
    const float* gatt = wf + off[20], *gb   = wf + off[21];
    const float* fcW  = wf + off[22], *fcb  = wf + off[23];
    const float* clf  = wf + off[24];

    // ---- remaining workspace (keep 16B alignment) ----
    float* p = wf + o + ((4 - (o & 3)) & 3);
    size_t N128 = (size_t)N * 128;
    __half* hxl1 = (__half*)p;      p += (size_t)N * 64;    // conv1 xl fp16 [N,128]; later global xl [N,32]
    float* fB1  = p;                p += N128;              // conv1 xr fp32; later global xrg [N,32]
    __half* hxl2 = (__half*)p;      p += (size_t)N * 64;    // conv2 xl fp16 [N,128]
    float* fB2  = p;                p += N128;              // conv2 xr fp32
    int* deg    = (int*)p;          // [N]
    int* st     = deg + N;          // [32] scan lookback state
    int* offs   = st + 32;          // N+1
    int* rank   = offs + N + 1;     // EA
    int* csr    = rank + EA;        // EA (src node ids)
    // transposed f16 weights (16B aligned)
    uintptr_t up = (uintptr_t)(csr + EA);
    up = (up + 15) & ~(uintptr_t)15;
    __half* a2Wlt = (__half*)up;    // [128][128]
    __half* a2Wrt = a2Wlt + 16384;  // [128][128]
    __half* gWlt  = a2Wrt + 16384;  // [32][128]
    __half* gWrt  = gWlt + 4096;    // [32][128]

    const int NB = (N + 1023) / 1024;          // scan tiles (20)
    const int EB = N / 32;                     // embedlin blocks (625)
    const int FBLK = (EA + 255) / 256;         // fill blocks
    const int GT = (N + 15) / 16;              // fused gather+linear tiles (1250)

    // ---- detect + zero deg/st ----
    k_detect_zero<<<64, 256, 0, stream>>>((const unsigned short*)d_in[0], flag, deg, N + 32);
    // ---- convert weights (+ f16 transposed) + degree count with rank capture
    k_convert<<<256, 256, 0, stream>>>(tab, wf, flag, dstArr, E, N, deg, rank,
                                       d_in[15], d_in[17], d_in[37], d_in[39],
                                       a2Wlt, a2Wrt, gWlt, gWrt);
    // ---- single-kernel lookback scan ----
    k_scanf<<<NB, 1024, 0, stream>>>(deg, offs, N, st, NB);
    // ---- CSR fill (rank trick) + fused embed+conv1-linear -> hxl1/fB1 ----
    k_fill_embedlin<<<EB + FBLK, 256, 0, stream>>>(srcArr, dstArr, E, N, offs, rank, csr,
                                                   d_in[0], flag, aeW, aeb,
                                                   a1Wl, a1bl, a1Wr, a1br, hxl1, fB1, EB);
    // ---- conv1 gather + conv2 linear (MFMA, fC stays in LDS) -> hxl2/fB2 ----
    k_gatlin<<<GT, 256, 0, stream>>>(hxl1, fB1, a1att, offs, csr, a1b,
                                     a2Wlt, a2bl, a2Wrt, a2br, hxl2, fB2, N);
    // ---- conv2 gather + global linear (MFMA) -> hxl1([N,32]) / fB1([N,32]) --
    k_gatling<<<GT, 256, 0, stream>>>(hxl2, fB2, a2att, offs, csr, a2b,
                                      gWlt, gbl, gWrt, gbr, hxl1, fB1, N);
    // ---- tail: global gather for the 64 focal dsts + head ----
    k_tailf<<<B, 64, 0, stream>>>(hxl1, fB1, gatt, offs, csr, gb, focal,
                                  clf, clW, clb, fcW, fcb, d_out, flag);
}